// Round 8
// baseline (373.152 us; speedup 1.0000x reference)
//
#include <hip/hip_runtime.h>
#include <hip/hip_bf16.h>
#include <math.h>

#define N_NODES    100000
#define N_EDGES    1600000
#define NUM_GRAPHS 512
#define D2 50
#define D3 15
#define D5 10
#define NCLS 6
#define BN_EPS 1e-5f

#define NBLK1 ((N_NODES + 1023) / 1024)   // 98 scan blocks

// global bf16 weight buffer layout (elements), padded/transposed
// ew1T [64 m][40 k] : k0-2 x_row, k3 bias, k4-6 x_col, k8-10 ea
// ew2T [16 m][72 k] : k0-49 h1, k50 bias
// nw1T [64 m][40 k] : k0-14 e2, k16-18 x_col, k19 bias
// nw2T [16 m][72 k] : k0-49 h2, k50 bias
#define W_EW1T 0
#define W_EW2T 2560
#define W_NW1T 3712
#define W_NW2T 6272
#define W_TOTAL 7680

#define EDGE_BLOCKS 2500
#define EDGE_WAVES  (EDGE_BLOCKS * 4)        // 10000
#define TILES32     (N_EDGES / 32)           // 50000
#define EDGE_ITERS  (TILES32 / EDGE_WAVES)   // 5

typedef __attribute__((ext_vector_type(8))) short short8;
typedef __attribute__((ext_vector_type(4))) float float4_;
union BU { unsigned u[4]; short8 s; };
union FU { unsigned u; float f; };

__device__ __forceinline__ unsigned short f2bf(float f) {
    __hip_bfloat16 h = __float2bfloat16(f);
    union { __hip_bfloat16 h; unsigned short u; } c; c.h = h; return c.u;
}
__device__ __forceinline__ float bf2f(unsigned short u) {
    union { __hip_bfloat16 h; unsigned short u; } c; c.u = u;
    return __bfloat162float(c.h);
}
__device__ __forceinline__ unsigned int pkbf(float a, float b) {
    return (unsigned int)f2bf(a) | ((unsigned int)f2bf(b) << 16);
}
__device__ __forceinline__ unsigned bp(int s4, unsigned v) {
    return (unsigned)__builtin_amdgcn_ds_bpermute(s4, (int)v);
}
__device__ __forceinline__ float lo16(unsigned u) { FU c; c.u = u << 16; return c.f; }
__device__ __forceinline__ float hi16(unsigned u) { FU c; c.u = u & 0xFFFF0000u; return c.f; }

// ---------- fused prep: weight split/transpose + x pad + in-degree histogram ----------
__global__ __launch_bounds__(256) void prep_kernel(
    const float* __restrict__ ew1, const float* __restrict__ eb1,
    const float* __restrict__ ew2, const float* __restrict__ eb2,
    const float* __restrict__ nw1, const float* __restrict__ nb1,
    const float* __restrict__ nw2, const float* __restrict__ nb2,
    unsigned short* __restrict__ wh, unsigned short* __restrict__ wl,
    const float* __restrict__ x, ushort4* __restrict__ x4b,
    const int* __restrict__ edge_index, int* __restrict__ counts)
{
    int gtid = blockIdx.x * 256 + threadIdx.x;
    int gsz = gridDim.x * 256;

    for (int i = gtid; i < W_TOTAL; i += gsz) {
        float v = 0.0f;
        if (i < W_EW2T) {
            int m = i / 40, k = i % 40;
            if (m < 50) {
                if (k < 3)                 v = ew1[k * 50 + m];
                else if (k == 3)           v = eb1[m];
                else if (k >= 4 && k < 7)  v = ew1[(k - 1) * 50 + m];
                else if (k >= 8 && k < 11) v = ew1[(k - 2) * 50 + m];
            }
        } else if (i < W_NW1T) {
            int j = i - W_EW2T; int m = j / 72, k = j % 72;
            if (m < 15) { if (k < 50) v = ew2[k * 15 + m]; else if (k == 50) v = eb2[m]; }
        } else if (i < W_NW2T) {
            int j = i - W_NW1T; int m = j / 40, k = j % 40;
            if (m < 50) {
                if (k < 15)                  v = nw1[(3 + k) * 50 + m];
                else if (k >= 16 && k < 19)  v = nw1[(k - 16) * 50 + m];
                else if (k == 19)            v = nb1[m];
            }
        } else if (i < 7424) {
            int j = i - W_NW2T; int m = j / 72, k = j % 72;
            if (m < 15) { if (k < 50) v = nw2[k * 15 + m]; else if (k == 50) v = nb2[m]; }
        }
        unsigned short h = f2bf(v);
        unsigned short l = f2bf(v - bf2f(h));
        wh[i] = h; wl[i] = l;
    }

    for (int n = gtid; n < N_NODES; n += gsz) {
        ushort4 v;
        v.x = f2bf(x[n * 3 + 0]); v.y = f2bf(x[n * 3 + 1]);
        v.z = f2bf(x[n * 3 + 2]); v.w = 0;
        x4b[n] = v;
    }

    for (int e = gtid; e < N_EDGES; e += gsz)
        atomicAdd(&counts[edge_index[e]], 1);
}

// ---------- CSR offsets (wave-shuffle scan, 2 barriers) ----------
__global__ __launch_bounds__(1024) void scan1_kernel(
    const int* __restrict__ counts, int* __restrict__ scanned, int* __restrict__ bsums)
{
    __shared__ int wsum[16], wofs[16];
    int i = blockIdx.x * 1024 + threadIdx.x;
    int lane = threadIdx.x & 63, wid = threadIdx.x >> 6;
    int v = (i < N_NODES) ? counts[i] : 0;
    int sc = v;
    #pragma unroll
    for (int off = 1; off < 64; off <<= 1) {
        int t = __shfl_up(sc, off);
        if (lane >= off) sc += t;
    }
    if (lane == 63) wsum[wid] = sc;
    __syncthreads();
    if (wid == 0) {
        int s = (lane < 16) ? wsum[lane] : 0;
        #pragma unroll
        for (int off = 1; off < 16; off <<= 1) {
            int t = __shfl_up(s, off);
            if (lane >= off) s += t;
        }
        if (lane < 16) wofs[lane] = s - wsum[lane];
    }
    __syncthreads();
    int incl = sc + wofs[wid];
    if (i < N_NODES) scanned[i] = incl - v;
    if (threadIdx.x == 1023) bsums[blockIdx.x] = incl;
}

__global__ __launch_bounds__(128) void scan2_kernel(
    const int* __restrict__ bsums, int* __restrict__ bofs)
{
    __shared__ int tmp[128];
    int v = (threadIdx.x < NBLK1) ? bsums[threadIdx.x] : 0;
    tmp[threadIdx.x] = v;
    __syncthreads();
    #pragma unroll
    for (int off = 1; off < 128; off <<= 1) {
        int t = (threadIdx.x >= off) ? tmp[threadIdx.x - off] : 0;
        __syncthreads();
        tmp[threadIdx.x] += t;
        __syncthreads();
    }
    if (threadIdx.x < NBLK1) bofs[threadIdx.x] = tmp[threadIdx.x] - v;
}

__global__ __launch_bounds__(256) void scan3_kernel(
    const int* __restrict__ scanned, const int* __restrict__ bofs,
    int* __restrict__ cursor)
{
    int n = blockIdx.x * 256 + threadIdx.x;
    if (n >= N_NODES) return;
    cursor[n] = scanned[n] + bofs[n >> 10];
}

// ---------- per-edge input fetch: each (quad,n) lane owns edge n's slice ----------
struct EIn { unsigned w0, w1, w2, w3, h0, h1; int pos; };

__device__ __forceinline__ EIn load_in(int ebase, int n, int quad,
    const int* __restrict__ edge_index, const ushort4* __restrict__ x4b,
    const float* __restrict__ edge_attr, int* __restrict__ cursor)
{
    EIn r; r.w0 = r.w1 = r.w2 = r.w3 = 0; r.h0 = r.h1 = 0; r.pos = 0;
    int e = ebase + n;
    if (quad == 0) {
        int row = edge_index[e];
        int col = edge_index[N_EDGES + e];
        ushort4 xr = x4b[row];
        ushort4 xc = x4b[col];
        r.w0 = (unsigned)xr.x | ((unsigned)xr.y << 16);   // k0,k1 = x_row
        r.w1 = (unsigned)xr.z | (0x3F80u << 16);          // k2, k3=bias
        r.w2 = (unsigned)xc.x | ((unsigned)xc.y << 16);   // k4,k5 = x_col
        r.w3 = (unsigned)xc.z;                            // k6, k7=0
        r.pos = atomicAdd(&cursor[row], 1);
    } else if (quad == 1) {
        r.w0 = pkbf(edge_attr[e * 3 + 0], edge_attr[e * 3 + 1]);  // k8,k9
        r.w1 = (unsigned)f2bf(edge_attr[e * 3 + 2]);              // k10, k11=0
    } else if (quad == 2) {
        int col = edge_index[N_EDGES + e];
        ushort4 xc = x4b[col];
        r.h0 = (unsigned)xc.x | ((unsigned)xc.y << 16);   // nodeMLP k16,k17
        r.h1 = (unsigned)xc.z | (0x3F80u << 16);          // k18, k19=bias
    }
    return r;
}

// 64-ch C output (4 blocks, packed pairs U[4][2]) -> two K=32 B fragments
__device__ __forceinline__ void perm64(const unsigned U[4][2], int s0, int s1, bool hi,
                                       short8& Bc0, short8& Bc1)
{
    BU b0, b1;
    {
        unsigned a0 = bp(s0, U[0][0]), a1 = bp(s0, U[1][0]);
        unsigned a2 = bp(s0, U[0][1]), a3 = bp(s0, U[1][1]);
        unsigned a4 = bp(s1, U[0][0]), a5 = bp(s1, U[1][0]);
        unsigned a6 = bp(s1, U[0][1]), a7 = bp(s1, U[1][1]);
        b0.u[0] = hi ? a1 : a0;
        b0.u[1] = hi ? a3 : a2;
        b0.u[2] = hi ? a5 : a4;
        b0.u[3] = hi ? a7 : a6;
    }
    {
        unsigned a0 = bp(s0, U[2][0]), a1 = bp(s0, U[3][0]);
        unsigned a2 = bp(s0, U[2][1]), a3 = bp(s0, U[3][1]);
        unsigned a4 = bp(s1, U[2][0]), a5 = bp(s1, U[3][0]);
        unsigned a6 = bp(s1, U[2][1]), a7 = bp(s1, U[3][1]);
        b1.u[0] = hi ? a1 : a0;
        b1.u[1] = hi ? a3 : a2;
        b1.u[2] = hi ? a5 : a4;
        b1.u[3] = hi ? a7 : a6;
    }
    Bc0 = b0.s; Bc1 = b1.s;
}

// 16-ch C output (packed U2[2]) + static x_col/bias part -> K=32 B fragment
__device__ __forceinline__ short8 perm16(const unsigned U2[2], int s0, int s1,
                                         int quad, unsigned h0, unsigned h1)
{
    BU d;
    d.u[0] = bp(s0, U2[0]);
    d.u[1] = bp(s0, U2[1]);
    d.u[2] = bp(s1, U2[0]);
    d.u[3] = bp(s1, U2[1]);
    if (quad == 2) { d.u[0] = h0; d.u[1] = h1; d.u[2] = 0; d.u[3] = 0; }
    else if (quad == 3) { d.u[0] = 0; d.u[1] = 0; d.u[2] = 0; d.u[3] = 0; }
    return d.s;
}

// ---------- MFMA edge MLP: no LDS, layer transitions via ds_bpermute ----------
__global__ __launch_bounds__(256) void edge_mfma_kernel(
    const unsigned short* __restrict__ wh_g, const unsigned short* __restrict__ wl_g,
    const ushort4* __restrict__ x4b, const float* __restrict__ edge_attr,
    const int* __restrict__ edge_index,
    int* __restrict__ cursor, unsigned short* __restrict__ msgb)
{
    int tid = threadIdx.x, wave = tid >> 6, lane = tid & 63;
    int n = lane & 15, quad = lane >> 4;

    // A-fragments (weights) -> registers, once per wave
    short8 A1h[4], A1l[4], A3h[4], A3l[4];
    #pragma unroll
    for (int t4 = 0; t4 < 4; t4++) {
        int o1 = W_EW1T + (t4 * 16 + n) * 40 + quad * 8;
        A1h[t4] = *(const short8*)(wh_g + o1);
        A1l[t4] = *(const short8*)(wl_g + o1);
        int o3 = W_NW1T + (t4 * 16 + n) * 40 + quad * 8;
        A3h[t4] = *(const short8*)(wh_g + o3);
        A3l[t4] = *(const short8*)(wl_g + o3);
    }
    short8 A2h[2], A2l[2], A4h[2], A4l[2];
    #pragma unroll
    for (int kc = 0; kc < 2; kc++) {
        int o2 = W_EW2T + n * 72 + kc * 32 + quad * 8;
        A2h[kc] = *(const short8*)(wh_g + o2);
        A2l[kc] = *(const short8*)(wl_g + o2);
        int o4 = W_NW2T + n * 72 + kc * 32 + quad * 8;
        A4h[kc] = *(const short8*)(wh_g + o4);
        A4l[kc] = *(const short8*)(wl_g + o4);
    }

    int s0 = ((quad & 1) * 32 + n) * 4;   // byte index for bpermute (lane*4)
    int s1 = s0 + 64;
    bool hi = (quad & 2) != 0;

    int t = blockIdx.x * 4 + wave;
    EIn cur0 = load_in(t * 32,      n, quad, edge_index, x4b, edge_attr, cursor);
    EIn cur1 = load_in(t * 32 + 16, n, quad, edge_index, x4b, edge_attr, cursor);

    for (int it = 0; it < EDGE_ITERS; it++) {
        int p0 = __shfl(cur0.pos, n);
        int p1 = __shfl(cur1.pos, n);

        int tn = t + EDGE_WAVES;
        EIn nx0, nx1;
        nx0.w0 = nx0.w1 = nx0.w2 = nx0.w3 = nx0.h0 = nx0.h1 = 0; nx0.pos = 0;
        nx1 = nx0;
        if (it + 1 < EDGE_ITERS) {
            nx0 = load_in(tn * 32,      n, quad, edge_index, x4b, edge_attr, cursor);
            nx1 = load_in(tn * 32 + 16, n, quad, edge_index, x4b, edge_attr, cursor);
        }

        // B1 direct from registers
        BU t0, t1;
        t0.u[0] = cur0.w0; t0.u[1] = cur0.w1; t0.u[2] = cur0.w2; t0.u[3] = cur0.w3;
        t1.u[0] = cur1.w0; t1.u[1] = cur1.w1; t1.u[2] = cur1.w2; t1.u[3] = cur1.w3;
        short8 B1a = t0.s, B1b = t1.s;

        // ---- layer 1: [64ch] x K=32 ----
        unsigned U1a[4][2], U1b[4][2];
        #pragma unroll
        for (int t4 = 0; t4 < 4; t4++) {
            float4_ za = {0.f, 0.f, 0.f, 0.f}, zb = {0.f, 0.f, 0.f, 0.f};
            za = __builtin_amdgcn_mfma_f32_16x16x32_bf16(A1l[t4], B1a, za, 0, 0, 0);
            zb = __builtin_amdgcn_mfma_f32_16x16x32_bf16(A1l[t4], B1b, zb, 0, 0, 0);
            za = __builtin_amdgcn_mfma_f32_16x16x32_bf16(A1h[t4], B1a, za, 0, 0, 0);
            zb = __builtin_amdgcn_mfma_f32_16x16x32_bf16(A1h[t4], B1b, zb, 0, 0, 0);
            U1a[t4][0] = pkbf(fmaxf(za[0], 0.f), fmaxf(za[1], 0.f));
            U1a[t4][1] = pkbf(fmaxf(za[2], 0.f), fmaxf(za[3], 0.f));
            U1b[t4][0] = pkbf(fmaxf(zb[0], 0.f), fmaxf(zb[1], 0.f));
            U1b[t4][1] = pkbf(fmaxf(zb[2], 0.f), fmaxf(zb[3], 0.f));
        }

        short8 B2a0, B2a1, B2b0, B2b1;
        perm64(U1a, s0, s1, hi, B2a0, B2a1);
        perm64(U1b, s0, s1, hi, B2b0, B2b1);
        // bias=1 at k=50: kc=1, quad_b=2, j=2 -> low half of uint[1]
        if (quad == 2) {
            BU fa, fb; fa.s = B2a1; fb.s = B2b1;
            fa.u[1] = (fa.u[1] & 0xFFFF0000u) | 0x3F80u;
            fb.u[1] = (fb.u[1] & 0xFFFF0000u) | 0x3F80u;
            B2a1 = fa.s; B2b1 = fb.s;
        }

        // ---- layer 2: [16ch] x K=64, split hi/lo accumulators ----
        float4_ a2al = {0.f, 0.f, 0.f, 0.f}, a2ah = {0.f, 0.f, 0.f, 0.f};
        float4_ a2bl = {0.f, 0.f, 0.f, 0.f}, a2bh = {0.f, 0.f, 0.f, 0.f};
        a2al = __builtin_amdgcn_mfma_f32_16x16x32_bf16(A2l[0], B2a0, a2al, 0, 0, 0);
        a2bl = __builtin_amdgcn_mfma_f32_16x16x32_bf16(A2l[0], B2b0, a2bl, 0, 0, 0);
        a2ah = __builtin_amdgcn_mfma_f32_16x16x32_bf16(A2h[0], B2a0, a2ah, 0, 0, 0);
        a2bh = __builtin_amdgcn_mfma_f32_16x16x32_bf16(A2h[0], B2b0, a2bh, 0, 0, 0);
        a2al = __builtin_amdgcn_mfma_f32_16x16x32_bf16(A2l[1], B2a1, a2al, 0, 0, 0);
        a2bl = __builtin_amdgcn_mfma_f32_16x16x32_bf16(A2l[1], B2b1, a2bl, 0, 0, 0);
        a2ah = __builtin_amdgcn_mfma_f32_16x16x32_bf16(A2h[1], B2a1, a2ah, 0, 0, 0);
        a2bh = __builtin_amdgcn_mfma_f32_16x16x32_bf16(A2h[1], B2b1, a2bh, 0, 0, 0);

        unsigned U2a[2] = { pkbf(a2al[0] + a2ah[0], a2al[1] + a2ah[1]),
                            pkbf(a2al[2] + a2ah[2], a2al[3] + a2ah[3]) };
        unsigned U2b[2] = { pkbf(a2bl[0] + a2bh[0], a2bl[1] + a2bh[1]),
                            pkbf(a2bl[2] + a2bh[2], a2bl[3] + a2bh[3]) };

        short8 B3a = perm16(U2a, s0, s1, quad, cur0.h0, cur0.h1);
        short8 B3b = perm16(U2b, s0, s1, quad, cur1.h0, cur1.h1);

        // ---- layer 3: [64ch] x K=32 ----
        unsigned U3a[4][2], U3b[4][2];
        #pragma unroll
        for (int t4 = 0; t4 < 4; t4++) {
            float4_ za = {0.f, 0.f, 0.f, 0.f}, zb = {0.f, 0.f, 0.f, 0.f};
            za = __builtin_amdgcn_mfma_f32_16x16x32_bf16(A3l[t4], B3a, za, 0, 0, 0);
            zb = __builtin_amdgcn_mfma_f32_16x16x32_bf16(A3l[t4], B3b, zb, 0, 0, 0);
            za = __builtin_amdgcn_mfma_f32_16x16x32_bf16(A3h[t4], B3a, za, 0, 0, 0);
            zb = __builtin_amdgcn_mfma_f32_16x16x32_bf16(A3h[t4], B3b, zb, 0, 0, 0);
            U3a[t4][0] = pkbf(fmaxf(za[0], 0.f), fmaxf(za[1], 0.f));
            U3a[t4][1] = pkbf(fmaxf(za[2], 0.f), fmaxf(za[3], 0.f));
            U3b[t4][0] = pkbf(fmaxf(zb[0], 0.f), fmaxf(zb[1], 0.f));
            U3b[t4][1] = pkbf(fmaxf(zb[2], 0.f), fmaxf(zb[3], 0.f));
        }

        short8 B4a0, B4a1, B4b0, B4b1;
        perm64(U3a, s0, s1, hi, B4a0, B4a1);
        perm64(U3b, s0, s1, hi, B4b0, B4b1);
        if (quad == 2) {
            BU fa, fb; fa.s = B4a1; fb.s = B4b1;
            fa.u[1] = (fa.u[1] & 0xFFFF0000u) | 0x3F80u;
            fb.u[1] = (fb.u[1] & 0xFFFF0000u) | 0x3F80u;
            B4a1 = fa.s; B4b1 = fb.s;
        }

        // ---- layer 4: [16ch] x K=64, split hi/lo accumulators ----
        float4_ mal = {0.f, 0.f, 0.f, 0.f}, mah = {0.f, 0.f, 0.f, 0.f};
        float4_ mbl = {0.f, 0.f, 0.f, 0.f}, mbh = {0.f, 0.f, 0.f, 0.f};
        mal = __builtin_amdgcn_mfma_f32_16x16x32_bf16(A4l[0], B4a0, mal, 0, 0, 0);
        mbl = __builtin_amdgcn_mfma_f32_16x16x32_bf16(A4l[0], B4b0, mbl, 0, 0, 0);
        mah = __builtin_amdgcn_mfma_f32_16x16x32_bf16(A4h[0], B4a0, mah, 0, 0, 0);
        mbh = __builtin_amdgcn_mfma_f32_16x16x32_bf16(A4h[0], B4b0, mbh, 0, 0, 0);
        mal = __builtin_amdgcn_mfma_f32_16x16x32_bf16(A4l[1], B4a1, mal, 0, 0, 0);
        mbl = __builtin_amdgcn_mfma_f32_16x16x32_bf16(A4l[1], B4b1, mbl, 0, 0, 0);
        mah = __builtin_amdgcn_mfma_f32_16x16x32_bf16(A4h[1], B4a1, mah, 0, 0, 0);
        mbh = __builtin_amdgcn_mfma_f32_16x16x32_bf16(A4h[1], B4b1, mbh, 0, 0, 0);

        // bf16 msg: 16 ch * 2B = 32 B/edge; lane writes its 4 channels (8 B)
        uint2 pa, pb;
        pa.x = pkbf(mal[0] + mah[0], mal[1] + mah[1]);
        pa.y = pkbf(mal[2] + mah[2], mal[3] + mah[3]);
        pb.x = pkbf(mbl[0] + mbh[0], mbl[1] + mbh[1]);
        pb.y = pkbf(mbl[2] + mbh[2], mbl[3] + mbh[3]);
        *(uint2*)(msgb + (size_t)p0 * 16 + quad * 4) = pa;
        *(uint2*)(msgb + (size_t)p1 * 16 + quad * 4) = pb;

        cur0 = nx0; cur1 = nx1; t = tn;
    }
}

// ---------- fused gather (CSR segment mean) + pool (sorted batch) ----------
__global__ __launch_bounds__(256) void gather_pool_kernel(
    const unsigned short* __restrict__ msgb, const int* __restrict__ scanned,
    const int* __restrict__ bofs, const int* __restrict__ counts,
    const int* __restrict__ batch, float* __restrict__ gsum)
{
    __shared__ float acc[64 * 16];
    int n0 = blockIdx.x * 256;
    int n = n0 + threadIdx.x;

    float v[16];
    #pragma unroll
    for (int k = 0; k < 16; k++) v[k] = 0.0f;
    if (n < N_NODES) {
        int start = scanned[n] + bofs[n >> 10];
        int deg = counts[n];
        for (int j = 0; j < deg; j++) {
            const uint4* mp = (const uint4*)(msgb + (size_t)(start + j) * 16);
            uint4 qa = mp[0], qb = mp[1];
            v[0]  += lo16(qa.x); v[1]  += hi16(qa.x);
            v[2]  += lo16(qa.y); v[3]  += hi16(qa.y);
            v[4]  += lo16(qa.z); v[5]  += hi16(qa.z);
            v[6]  += lo16(qa.w); v[7]  += hi16(qa.w);
            v[8]  += lo16(qb.x); v[9]  += hi16(qb.x);
            v[10] += lo16(qb.y); v[11] += hi16(qb.y);
            v[12] += lo16(qb.z); v[13] += hi16(qb.z);
            v[14] += lo16(qb.w);
        }
        float inv = 1.0f / fmaxf((float)deg, 1.0f);
        #pragma unroll
        for (int k = 0; k < 15; k++) v[k] *= inv;
        v[15] = 1.0f;   // node count
    }

    int gmin = batch[n0];
    int gmax = batch[min(n0 + 255, N_NODES - 1)];
    int range = gmax - gmin + 1;
    if (range <= 64) {
        for (int t = threadIdx.x; t < range * 16; t += 256) acc[t] = 0.0f;
        __syncthreads();
        if (n < N_NODES) {
            int g = batch[n] - gmin;
            float* dst = &acc[g * 16];
            #pragma unroll
            for (int k = 0; k < 16; k++) atomicAdd(&dst[k], v[k]);
        }
        __syncthreads();
        for (int t = threadIdx.x; t < range * 16; t += 256) {
            float w = acc[t];
            if (w != 0.0f) atomicAdd(&gsum[(size_t)gmin * 16 + t], w);
        }
    } else {
        if (n < N_NODES) {
            int g = batch[n];
            float* dst = gsum + (size_t)g * 16;
            #pragma unroll
            for (int k = 0; k < 16; k++) atomicAdd(&dst[k], v[k]);
        }
    }
}

// ---------- head ----------
__global__ __launch_bounds__(512) void head_kernel(
    const float* __restrict__ gsum,
    const float* __restrict__ fc1w, const float* __restrict__ fc1b,
    const float* __restrict__ gamma, const float* __restrict__ beta,
    const float* __restrict__ fc2w, const float* __restrict__ fc2b,
    float* __restrict__ out)
{
    __shared__ float ssum[D5], ssq[D5], smu[D5], sistd[D5];
    int g = threadIdx.x;
    if (g < D5) { ssum[g] = 0.0f; ssq[g] = 0.0f; }
    __syncthreads();

    const float* src = gsum + (size_t)g * 16;
    float inv = 1.0f / fmaxf(src[15], 1.0f);
    float u[D3];
    #pragma unroll
    for (int k = 0; k < D3; k++) u[k] = src[k] * inv;

    float h[D5];
    #pragma unroll
    for (int c = 0; c < D5; c++) h[c] = fc1b[c];
    #pragma unroll
    for (int k = 0; k < D3; k++) {
        float v = u[k];
        #pragma unroll
        for (int c = 0; c < D5; c++) h[c] = fmaf(v, fc1w[k * D5 + c], h[c]);
    }

    int lane = threadIdx.x & 63;
    #pragma unroll
    for (int c = 0; c < D5; c++) {
        float v = h[c];
        float v2 = v * v;
        #pragma unroll
        for (int off = 32; off >= 1; off >>= 1) {
            v  += __shfl_xor(v,  off);
            v2 += __shfl_xor(v2, off);
        }
        if (lane == 0) { atomicAdd(&ssum[c], v); atomicAdd(&ssq[c], v2); }
    }
    __syncthreads();
    if (g < D5) {
        float mu = ssum[g] * (1.0f / NUM_GRAPHS);
        float var = ssq[g] * (1.0f / NUM_GRAPHS) - mu * mu;
        smu[g] = mu;
        sistd[g] = rsqrtf(var + BN_EPS);
    }
    __syncthreads();

    float hn[D5];
    #pragma unroll
    for (int c = 0; c < D5; c++) {
        float v = gamma[c] * (h[c] - smu[c]) * sistd[c] + beta[c];
        hn[c] = fmaxf(v, 0.0f);
    }

    float lg[NCLS];
    #pragma unroll
    for (int j = 0; j < NCLS; j++) lg[j] = fc2b[j];
    #pragma unroll
    for (int c = 0; c < D5; c++) {
        float v = hn[c];
        #pragma unroll
        for (int j = 0; j < NCLS; j++) lg[j] = fmaf(v, fc2w[c * NCLS + j], lg[j]);
    }

    float m = lg[0];
    #pragma unroll
    for (int j = 1; j < NCLS; j++) m = fmaxf(m, lg[j]);
    float se = 0.0f;
    #pragma unroll
    for (int j = 0; j < NCLS; j++) se += expf(lg[j] - m);
    float lse = logf(se);
    #pragma unroll
    for (int j = 0; j < NCLS; j++) out[g * NCLS + j] = lg[j] - m - lse;
}

extern "C" void kernel_launch(void* const* d_in, const int* in_sizes, int n_in,
                              void* d_out, int out_size, void* d_ws, size_t ws_size,
                              hipStream_t stream) {
    const float* x         = (const float*)d_in[0];
    const float* edge_attr = (const float*)d_in[1];
    const float* ew1  = (const float*)d_in[2];
    const float* eb1  = (const float*)d_in[3];
    const float* ew2  = (const float*)d_in[4];
    const float* eb2  = (const float*)d_in[5];
    const float* nw1  = (const float*)d_in[6];
    const float* nb1  = (const float*)d_in[7];
    const float* nw2  = (const float*)d_in[8];
    const float* nb2  = (const float*)d_in[9];
    const float* fc1w = (const float*)d_in[10];
    const float* fc1b = (const float*)d_in[11];
    const float* gamma= (const float*)d_in[12];
    const float* beta = (const float*)d_in[13];
    const float* fc2w = (const float*)d_in[14];
    const float* fc2b = (const float*)d_in[15];
    const int* edge_index = (const int*)d_in[16];
    const int* batch      = (const int*)d_in[17];

    // workspace layout
    char* p = (char*)d_ws;
    unsigned short* msgb = (unsigned short*)p; p += (size_t)N_EDGES * 16 * sizeof(unsigned short); // 51.2 MB
    int* counts  = (int*)p;            p += (size_t)N_NODES * sizeof(int);
    int* scanned = (int*)p;            p += (size_t)N_NODES * sizeof(int);
    int* cursor  = (int*)p;            p += (size_t)N_NODES * sizeof(int);
    int* bsums   = (int*)p;            p += 128 * sizeof(int);
    int* bofs    = (int*)p;            p += 128 * sizeof(int);
    ushort4* x4b = (ushort4*)p;        p += (size_t)N_NODES * sizeof(ushort4);     // 0.8 MB
    float* gsum  = (float*)p;          p += (size_t)NUM_GRAPHS * 16 * sizeof(float);
    unsigned short* wh = (unsigned short*)p; p += W_TOTAL * sizeof(unsigned short);
    unsigned short* wl = (unsigned short*)p; p += W_TOTAL * sizeof(unsigned short);

    hipMemsetAsync(counts, 0, (size_t)N_NODES * sizeof(int), stream);
    hipMemsetAsync(gsum, 0, (size_t)NUM_GRAPHS * 16 * sizeof(float), stream);

    int egrid = (N_EDGES + 255) / 256;
    int ngrid = (N_NODES + 255) / 256;

    prep_kernel<<<egrid, 256, 0, stream>>>(
        ew1, eb1, ew2, eb2, nw1, nb1, nw2, nb2, wh, wl,
        x, x4b, edge_index, counts);
    scan1_kernel<<<NBLK1, 1024, 0, stream>>>(counts, scanned, bsums);
    scan2_kernel<<<1, 128, 0, stream>>>(bsums, bofs);
    scan3_kernel<<<ngrid, 256, 0, stream>>>(scanned, bofs, cursor);
    edge_mfma_kernel<<<EDGE_BLOCKS, 256, 0, stream>>>(
        wh, wl, x4b, edge_attr, edge_index, cursor, msgb);
    gather_pool_kernel<<<ngrid, 256, 0, stream>>>(
        msgb, scanned, bofs, counts, batch, gsum);
    head_kernel<<<1, 512, 0, stream>>>(
        gsum, fc1w, fc1b, gamma, beta, fc2w, fc2b, (float*)d_out);
}

// Round 9
// 344.777 us; speedup vs baseline: 1.0823x; 1.0823x over previous
//
#include <hip/hip_runtime.h>
#include <hip/hip_bf16.h>
#include <math.h>

#define N_NODES    100000
#define N_EDGES    1600000
#define NUM_GRAPHS 512
#define D2 50
#define D3 15
#define D5 10
#define NCLS 6
#define BN_EPS 1e-5f

#define NBLK1 ((N_NODES + 1023) / 1024)   // 98 scan blocks

// global bf16 weight buffer layout (elements), padded/transposed
// ew1T [64 m][40 k] : k0-2 x_row, k3 bias, k4-6 x_col, k8-10 ea
// ew2T [16 m][72 k] : k0-49 h1, k50 bias
// nw1T [64 m][40 k] : k0-14 e2, k16-18 x_col, k19 bias
// nw2T [16 m][72 k] : k0-49 h2, k50 bias
#define W_EW1T 0
#define W_EW2T 2560
#define W_NW1T 3712
#define W_NW2T 6272
#define W_TOTAL 7680

#define EDGE_BLOCKS 2500
#define EDGE_WAVES  (EDGE_BLOCKS * 4)        // 10000
#define TILES32     (N_EDGES / 32)           // 50000
#define EDGE_ITERS  (TILES32 / EDGE_WAVES)   // 5

typedef __attribute__((ext_vector_type(8))) short short8;
typedef __attribute__((ext_vector_type(4))) float float4_;
union BU { unsigned u[4]; short8 s; };
union FU { unsigned u; float f; };

__device__ __forceinline__ unsigned short f2bf(float f) {
    __hip_bfloat16 h = __float2bfloat16(f);
    union { __hip_bfloat16 h; unsigned short u; } c; c.h = h; return c.u;
}
__device__ __forceinline__ float bf2f(unsigned short u) {
    union { __hip_bfloat16 h; unsigned short u; } c; c.u = u;
    return __bfloat162float(c.h);
}
__device__ __forceinline__ unsigned int pkbf(float a, float b) {
    return (unsigned int)f2bf(a) | ((unsigned int)f2bf(b) << 16);
}
__device__ __forceinline__ unsigned bp(int s4, unsigned v) {
    return (unsigned)__builtin_amdgcn_ds_bpermute(s4, (int)v);
}
__device__ __forceinline__ float lo16(unsigned u) { FU c; c.u = u << 16; return c.f; }
__device__ __forceinline__ float hi16(unsigned u) { FU c; c.u = u & 0xFFFF0000u; return c.f; }

// ---------- fused prep: weight split/transpose + x pad + in-degree histogram ----------
__global__ __launch_bounds__(256) void prep_kernel(
    const float* __restrict__ ew1, const float* __restrict__ eb1,
    const float* __restrict__ ew2, const float* __restrict__ eb2,
    const float* __restrict__ nw1, const float* __restrict__ nb1,
    const float* __restrict__ nw2, const float* __restrict__ nb2,
    unsigned short* __restrict__ wh, unsigned short* __restrict__ wl,
    const float* __restrict__ x, ushort4* __restrict__ x4b,
    const int* __restrict__ edge_index, int* __restrict__ counts)
{
    int gtid = blockIdx.x * 256 + threadIdx.x;
    int gsz = gridDim.x * 256;

    for (int i = gtid; i < W_TOTAL; i += gsz) {
        float v = 0.0f;
        if (i < W_EW2T) {
            int m = i / 40, k = i % 40;
            if (m < 50) {
                if (k < 3)                 v = ew1[k * 50 + m];
                else if (k == 3)           v = eb1[m];
                else if (k >= 4 && k < 7)  v = ew1[(k - 1) * 50 + m];
                else if (k >= 8 && k < 11) v = ew1[(k - 2) * 50 + m];
            }
        } else if (i < W_NW1T) {
            int j = i - W_EW2T; int m = j / 72, k = j % 72;
            if (m < 15) { if (k < 50) v = ew2[k * 15 + m]; else if (k == 50) v = eb2[m]; }
        } else if (i < W_NW2T) {
            int j = i - W_NW1T; int m = j / 40, k = j % 40;
            if (m < 50) {
                if (k < 15)                  v = nw1[(3 + k) * 50 + m];
                else if (k >= 16 && k < 19)  v = nw1[(k - 16) * 50 + m];
                else if (k == 19)            v = nb1[m];
            }
        } else if (i < 7424) {
            int j = i - W_NW2T; int m = j / 72, k = j % 72;
            if (m < 15) { if (k < 50) v = nw2[k * 15 + m]; else if (k == 50) v = nb2[m]; }
        }
        unsigned short h = f2bf(v);
        unsigned short l = f2bf(v - bf2f(h));
        wh[i] = h; wl[i] = l;
    }

    for (int n = gtid; n < N_NODES; n += gsz) {
        ushort4 v;
        v.x = f2bf(x[n * 3 + 0]); v.y = f2bf(x[n * 3 + 1]);
        v.z = f2bf(x[n * 3 + 2]); v.w = 0;
        x4b[n] = v;
    }

    for (int e = gtid; e < N_EDGES; e += gsz)
        atomicAdd(&counts[edge_index[e]], 1);
}

// ---------- CSR offsets (wave-shuffle scan) ----------
__global__ __launch_bounds__(1024) void scan1_kernel(
    const int* __restrict__ counts, int* __restrict__ scanned, int* __restrict__ bsums)
{
    __shared__ int wsum[16], wofs[16];
    int i = blockIdx.x * 1024 + threadIdx.x;
    int lane = threadIdx.x & 63, wid = threadIdx.x >> 6;
    int v = (i < N_NODES) ? counts[i] : 0;
    int sc = v;
    #pragma unroll
    for (int off = 1; off < 64; off <<= 1) {
        int t = __shfl_up(sc, off);
        if (lane >= off) sc += t;
    }
    if (lane == 63) wsum[wid] = sc;
    __syncthreads();
    if (wid == 0) {
        int s = (lane < 16) ? wsum[lane] : 0;
        #pragma unroll
        for (int off = 1; off < 16; off <<= 1) {
            int t = __shfl_up(s, off);
            if (lane >= off) s += t;
        }
        if (lane < 16) wofs[lane] = s - wsum[lane];
    }
    __syncthreads();
    int incl = sc + wofs[wid];
    if (i < N_NODES) scanned[i] = incl - v;
    if (threadIdx.x == 1023) bsums[blockIdx.x] = incl;
}

__global__ __launch_bounds__(128) void scan2_kernel(
    const int* __restrict__ bsums, int* __restrict__ bofs)
{
    __shared__ int tmp[128];
    int v = (threadIdx.x < NBLK1) ? bsums[threadIdx.x] : 0;
    tmp[threadIdx.x] = v;
    __syncthreads();
    #pragma unroll
    for (int off = 1; off < 128; off <<= 1) {
        int t = (threadIdx.x >= off) ? tmp[threadIdx.x - off] : 0;
        __syncthreads();
        tmp[threadIdx.x] += t;
        __syncthreads();
    }
    if (threadIdx.x < NBLK1) bofs[threadIdx.x] = tmp[threadIdx.x] - v;
}

__global__ __launch_bounds__(256) void scan3_kernel(
    const int* __restrict__ scanned, const int* __restrict__ bofs,
    int* __restrict__ cursor)
{
    int n = blockIdx.x * 256 + threadIdx.x;
    if (n >= N_NODES) return;
    cursor[n] = scanned[n] + bofs[n >> 10];
}

// ---------- per-edge input fetch: each (quad,n) lane owns edge n's slice ----------
struct EIn { unsigned w0, w1, w2, w3, h0, h1; int pos; };

__device__ __forceinline__ EIn load_in(int ebase, int n, int quad,
    const int* __restrict__ edge_index, const ushort4* __restrict__ x4b,
    const float* __restrict__ edge_attr, int* __restrict__ cursor)
{
    EIn r; r.w0 = r.w1 = r.w2 = r.w3 = 0; r.h0 = r.h1 = 0; r.pos = 0;
    int e = ebase + n;
    if (quad == 0) {
        int row = edge_index[e];
        int col = edge_index[N_EDGES + e];
        ushort4 xr = x4b[row];
        ushort4 xc = x4b[col];
        r.w0 = (unsigned)xr.x | ((unsigned)xr.y << 16);   // k0,k1 = x_row
        r.w1 = (unsigned)xr.z | (0x3F80u << 16);          // k2, k3=bias
        r.w2 = (unsigned)xc.x | ((unsigned)xc.y << 16);   // k4,k5 = x_col
        r.w3 = (unsigned)xc.z;                            // k6, k7=0
        r.pos = atomicAdd(&cursor[row], 1);
    } else if (quad == 1) {
        r.w0 = pkbf(edge_attr[e * 3 + 0], edge_attr[e * 3 + 1]);  // k8,k9
        r.w1 = (unsigned)f2bf(edge_attr[e * 3 + 2]);              // k10, k11=0
    } else if (quad == 2) {
        int col = edge_index[N_EDGES + e];
        ushort4 xc = x4b[col];
        r.h0 = (unsigned)xc.x | ((unsigned)xc.y << 16);   // nodeMLP k16,k17
        r.h1 = (unsigned)xc.z | (0x3F80u << 16);          // k18, k19=bias
    }
    return r;
}

// 64-ch C output (4 blocks, packed pairs U[4][2]) -> two K=32 B fragments
__device__ __forceinline__ void perm64(const unsigned U[4][2], int s0, int s1, bool hi,
                                       short8& Bc0, short8& Bc1)
{
    BU b0, b1;
    {
        unsigned a0 = bp(s0, U[0][0]), a1 = bp(s0, U[1][0]);
        unsigned a2 = bp(s0, U[0][1]), a3 = bp(s0, U[1][1]);
        unsigned a4 = bp(s1, U[0][0]), a5 = bp(s1, U[1][0]);
        unsigned a6 = bp(s1, U[0][1]), a7 = bp(s1, U[1][1]);
        b0.u[0] = hi ? a1 : a0;
        b0.u[1] = hi ? a3 : a2;
        b0.u[2] = hi ? a5 : a4;
        b0.u[3] = hi ? a7 : a6;
    }
    {
        unsigned a0 = bp(s0, U[2][0]), a1 = bp(s0, U[3][0]);
        unsigned a2 = bp(s0, U[2][1]), a3 = bp(s0, U[3][1]);
        unsigned a4 = bp(s1, U[2][0]), a5 = bp(s1, U[3][0]);
        unsigned a6 = bp(s1, U[2][1]), a7 = bp(s1, U[3][1]);
        b1.u[0] = hi ? a1 : a0;
        b1.u[1] = hi ? a3 : a2;
        b1.u[2] = hi ? a5 : a4;
        b1.u[3] = hi ? a7 : a6;
    }
    Bc0 = b0.s; Bc1 = b1.s;
}

// 16-ch C output (packed U2[2]) + static x_col/bias part -> K=32 B fragment
__device__ __forceinline__ short8 perm16(const unsigned U2[2], int s0, int s1,
                                         int quad, unsigned h0, unsigned h1)
{
    BU d;
    d.u[0] = bp(s0, U2[0]);
    d.u[1] = bp(s0, U2[1]);
    d.u[2] = bp(s1, U2[0]);
    d.u[3] = bp(s1, U2[1]);
    if (quad == 2) { d.u[0] = h0; d.u[1] = h1; d.u[2] = 0; d.u[3] = 0; }
    else if (quad == 3) { d.u[0] = 0; d.u[1] = 0; d.u[2] = 0; d.u[3] = 0; }
    return d.s;
}

// ---------- MFMA edge MLP: no LDS, bpermute transitions, weights resident ----------
// __launch_bounds__(256, 2): 2 waves/EU -> VGPR budget 256, keeps the 96 VGPRs
// of weight fragments resident instead of refetching per iteration (R7/R8 had
// VGPR_Count 80-88 < 96 => compiler was reloading weights inside the loop).
__global__ __launch_bounds__(256, 2) void edge_mfma_kernel(
    const unsigned short* __restrict__ wh_g, const unsigned short* __restrict__ wl_g,
    const ushort4* __restrict__ x4b, const float* __restrict__ edge_attr,
    const int* __restrict__ edge_index,
    int* __restrict__ cursor, unsigned short* __restrict__ msgb)
{
    int tid = threadIdx.x, wave = tid >> 6, lane = tid & 63;
    int n = lane & 15, quad = lane >> 4;

    // A-fragments (weights) -> registers, once per wave
    short8 A1h[4], A1l[4], A3h[4], A3l[4];
    #pragma unroll
    for (int t4 = 0; t4 < 4; t4++) {
        int o1 = W_EW1T + (t4 * 16 + n) * 40 + quad * 8;
        A1h[t4] = *(const short8*)(wh_g + o1);
        A1l[t4] = *(const short8*)(wl_g + o1);
        int o3 = W_NW1T + (t4 * 16 + n) * 40 + quad * 8;
        A3h[t4] = *(const short8*)(wh_g + o3);
        A3l[t4] = *(const short8*)(wl_g + o3);
    }
    short8 A2h[2], A2l[2], A4h[2], A4l[2];
    #pragma unroll
    for (int kc = 0; kc < 2; kc++) {
        int o2 = W_EW2T + n * 72 + kc * 32 + quad * 8;
        A2h[kc] = *(const short8*)(wh_g + o2);
        A2l[kc] = *(const short8*)(wl_g + o2);
        int o4 = W_NW2T + n * 72 + kc * 32 + quad * 8;
        A4h[kc] = *(const short8*)(wh_g + o4);
        A4l[kc] = *(const short8*)(wl_g + o4);
    }

    int s0 = ((quad & 1) * 32 + n) * 4;   // byte index for bpermute (lane*4)
    int s1 = s0 + 64;
    bool hi = (quad & 2) != 0;

    int t = blockIdx.x * 4 + wave;
    EIn cur0 = load_in(t * 32,      n, quad, edge_index, x4b, edge_attr, cursor);
    EIn cur1 = load_in(t * 32 + 16, n, quad, edge_index, x4b, edge_attr, cursor);

    for (int it = 0; it < EDGE_ITERS; it++) {
        int p0 = __shfl(cur0.pos, n);
        int p1 = __shfl(cur1.pos, n);

        int tn = t + EDGE_WAVES;
        EIn nx0, nx1;
        nx0.w0 = nx0.w1 = nx0.w2 = nx0.w3 = nx0.h0 = nx0.h1 = 0; nx0.pos = 0;
        nx1 = nx0;
        if (it + 1 < EDGE_ITERS) {
            nx0 = load_in(tn * 32,      n, quad, edge_index, x4b, edge_attr, cursor);
            nx1 = load_in(tn * 32 + 16, n, quad, edge_index, x4b, edge_attr, cursor);
        }

        // B1 direct from registers
        BU t0, t1;
        t0.u[0] = cur0.w0; t0.u[1] = cur0.w1; t0.u[2] = cur0.w2; t0.u[3] = cur0.w3;
        t1.u[0] = cur1.w0; t1.u[1] = cur1.w1; t1.u[2] = cur1.w2; t1.u[3] = cur1.w3;
        short8 B1a = t0.s, B1b = t1.s;

        // ---- layer 1: [64ch] x K=32 ----
        unsigned U1a[4][2], U1b[4][2];
        #pragma unroll
        for (int t4 = 0; t4 < 4; t4++) {
            float4_ za = {0.f, 0.f, 0.f, 0.f}, zb = {0.f, 0.f, 0.f, 0.f};
            za = __builtin_amdgcn_mfma_f32_16x16x32_bf16(A1l[t4], B1a, za, 0, 0, 0);
            zb = __builtin_amdgcn_mfma_f32_16x16x32_bf16(A1l[t4], B1b, zb, 0, 0, 0);
            za = __builtin_amdgcn_mfma_f32_16x16x32_bf16(A1h[t4], B1a, za, 0, 0, 0);
            zb = __builtin_amdgcn_mfma_f32_16x16x32_bf16(A1h[t4], B1b, zb, 0, 0, 0);
            U1a[t4][0] = pkbf(fmaxf(za[0], 0.f), fmaxf(za[1], 0.f));
            U1a[t4][1] = pkbf(fmaxf(za[2], 0.f), fmaxf(za[3], 0.f));
            U1b[t4][0] = pkbf(fmaxf(zb[0], 0.f), fmaxf(zb[1], 0.f));
            U1b[t4][1] = pkbf(fmaxf(zb[2], 0.f), fmaxf(zb[3], 0.f));
        }

        short8 B2a0, B2a1, B2b0, B2b1;
        perm64(U1a, s0, s1, hi, B2a0, B2a1);
        perm64(U1b, s0, s1, hi, B2b0, B2b1);
        // bias=1 at k=50: kc=1, quad_b=2, j=2 -> low half of uint[1]
        if (quad == 2) {
            BU fa, fb; fa.s = B2a1; fb.s = B2b1;
            fa.u[1] = (fa.u[1] & 0xFFFF0000u) | 0x3F80u;
            fb.u[1] = (fb.u[1] & 0xFFFF0000u) | 0x3F80u;
            B2a1 = fa.s; B2b1 = fb.s;
        }

        // ---- layer 2: [16ch] x K=64, split hi/lo accumulators ----
        float4_ a2al = {0.f, 0.f, 0.f, 0.f}, a2ah = {0.f, 0.f, 0.f, 0.f};
        float4_ a2bl = {0.f, 0.f, 0.f, 0.f}, a2bh = {0.f, 0.f, 0.f, 0.f};
        a2al = __builtin_amdgcn_mfma_f32_16x16x32_bf16(A2l[0], B2a0, a2al, 0, 0, 0);
        a2bl = __builtin_amdgcn_mfma_f32_16x16x32_bf16(A2l[0], B2b0, a2bl, 0, 0, 0);
        a2ah = __builtin_amdgcn_mfma_f32_16x16x32_bf16(A2h[0], B2a0, a2ah, 0, 0, 0);
        a2bh = __builtin_amdgcn_mfma_f32_16x16x32_bf16(A2h[0], B2b0, a2bh, 0, 0, 0);
        a2al = __builtin_amdgcn_mfma_f32_16x16x32_bf16(A2l[1], B2a1, a2al, 0, 0, 0);
        a2bl = __builtin_amdgcn_mfma_f32_16x16x32_bf16(A2l[1], B2b1, a2bl, 0, 0, 0);
        a2ah = __builtin_amdgcn_mfma_f32_16x16x32_bf16(A2h[1], B2a1, a2ah, 0, 0, 0);
        a2bh = __builtin_amdgcn_mfma_f32_16x16x32_bf16(A2h[1], B2b1, a2bh, 0, 0, 0);

        unsigned U2a[2] = { pkbf(a2al[0] + a2ah[0], a2al[1] + a2ah[1]),
                            pkbf(a2al[2] + a2ah[2], a2al[3] + a2ah[3]) };
        unsigned U2b[2] = { pkbf(a2bl[0] + a2bh[0], a2bl[1] + a2bh[1]),
                            pkbf(a2bl[2] + a2bh[2], a2bl[3] + a2bh[3]) };

        short8 B3a = perm16(U2a, s0, s1, quad, cur0.h0, cur0.h1);
        short8 B3b = perm16(U2b, s0, s1, quad, cur1.h0, cur1.h1);

        // ---- layer 3: [64ch] x K=32 ----
        unsigned U3a[4][2], U3b[4][2];
        #pragma unroll
        for (int t4 = 0; t4 < 4; t4++) {
            float4_ za = {0.f, 0.f, 0.f, 0.f}, zb = {0.f, 0.f, 0.f, 0.f};
            za = __builtin_amdgcn_mfma_f32_16x16x32_bf16(A3l[t4], B3a, za, 0, 0, 0);
            zb = __builtin_amdgcn_mfma_f32_16x16x32_bf16(A3l[t4], B3b, zb, 0, 0, 0);
            za = __builtin_amdgcn_mfma_f32_16x16x32_bf16(A3h[t4], B3a, za, 0, 0, 0);
            zb = __builtin_amdgcn_mfma_f32_16x16x32_bf16(A3h[t4], B3b, zb, 0, 0, 0);
            U3a[t4][0] = pkbf(fmaxf(za[0], 0.f), fmaxf(za[1], 0.f));
            U3a[t4][1] = pkbf(fmaxf(za[2], 0.f), fmaxf(za[3], 0.f));
            U3b[t4][0] = pkbf(fmaxf(zb[0], 0.f), fmaxf(zb[1], 0.f));
            U3b[t4][1] = pkbf(fmaxf(zb[2], 0.f), fmaxf(zb[3], 0.f));
        }

        short8 B4a0, B4a1, B4b0, B4b1;
        perm64(U3a, s0, s1, hi, B4a0, B4a1);
        perm64(U3b, s0, s1, hi, B4b0, B4b1);
        if (quad == 2) {
            BU fa, fb; fa.s = B4a1; fb.s = B4b1;
            fa.u[1] = (fa.u[1] & 0xFFFF0000u) | 0x3F80u;
            fb.u[1] = (fb.u[1] & 0xFFFF0000u) | 0x3F80u;
            B4a1 = fa.s; B4b1 = fb.s;
        }

        // ---- layer 4: [16ch] x K=64, split hi/lo accumulators ----
        float4_ mal = {0.f, 0.f, 0.f, 0.f}, mah = {0.f, 0.f, 0.f, 0.f};
        float4_ mbl = {0.f, 0.f, 0.f, 0.f}, mbh = {0.f, 0.f, 0.f, 0.f};
        mal = __builtin_amdgcn_mfma_f32_16x16x32_bf16(A4l[0], B4a0, mal, 0, 0, 0);
        mbl = __builtin_amdgcn_mfma_f32_16x16x32_bf16(A4l[0], B4b0, mbl, 0, 0, 0);
        mah = __builtin_amdgcn_mfma_f32_16x16x32_bf16(A4h[0], B4a0, mah, 0, 0, 0);
        mbh = __builtin_amdgcn_mfma_f32_16x16x32_bf16(A4h[0], B4b0, mbh, 0, 0, 0);
        mal = __builtin_amdgcn_mfma_f32_16x16x32_bf16(A4l[1], B4a1, mal, 0, 0, 0);
        mbl = __builtin_amdgcn_mfma_f32_16x16x32_bf16(A4l[1], B4b1, mbl, 0, 0, 0);
        mah = __builtin_amdgcn_mfma_f32_16x16x32_bf16(A4h[1], B4a1, mah, 0, 0, 0);
        mbh = __builtin_amdgcn_mfma_f32_16x16x32_bf16(A4h[1], B4b1, mbh, 0, 0, 0);

        // bf16 msg: 16 ch * 2B = 32 B/edge; lane writes its 4 channels (8 B)
        uint2 pa, pb;
        pa.x = pkbf(mal[0] + mah[0], mal[1] + mah[1]);
        pa.y = pkbf(mal[2] + mah[2], mal[3] + mah[3]);
        pb.x = pkbf(mbl[0] + mbh[0], mbl[1] + mbh[1]);
        pb.y = pkbf(mbl[2] + mbh[2], mbl[3] + mbh[3]);
        *(uint2*)(msgb + (size_t)p0 * 16 + quad * 4) = pa;
        *(uint2*)(msgb + (size_t)p1 * 16 + quad * 4) = pb;

        cur0 = nx0; cur1 = nx1; t = tn;
    }
}

// ---------- fused gather (CSR segment mean) + pool (sorted batch) ----------
__global__ __launch_bounds__(256) void gather_pool_kernel(
    const unsigned short* __restrict__ msgb, const int* __restrict__ scanned,
    const int* __restrict__ bofs, const int* __restrict__ counts,
    const int* __restrict__ batch, float* __restrict__ gsum)
{
    __shared__ float acc[64 * 16];
    int n0 = blockIdx.x * 256;
    int n = n0 + threadIdx.x;

    float v[16];
    #pragma unroll
    for (int k = 0; k < 16; k++) v[k] = 0.0f;
    if (n < N_NODES) {
        int start = scanned[n] + bofs[n >> 10];
        int deg = counts[n];
        for (int j = 0; j < deg; j++) {
            const uint4* mp = (const uint4*)(msgb + (size_t)(start + j) * 16);
            uint4 qa = mp[0], qb = mp[1];
            v[0]  += lo16(qa.x); v[1]  += hi16(qa.x);
            v[2]  += lo16(qa.y); v[3]  += hi16(qa.y);
            v[4]  += lo16(qa.z); v[5]  += hi16(qa.z);
            v[6]  += lo16(qa.w); v[7]  += hi16(qa.w);
            v[8]  += lo16(qb.x); v[9]  += hi16(qb.x);
            v[10] += lo16(qb.y); v[11] += hi16(qb.y);
            v[12] += lo16(qb.z); v[13] += hi16(qb.z);
            v[14] += lo16(qb.w);
        }
        float inv = 1.0f / fmaxf((float)deg, 1.0f);
        #pragma unroll
        for (int k = 0; k < 15; k++) v[k] *= inv;
        v[15] = 1.0f;   // node count
    }

    int gmin = batch[n0];
    int gmax = batch[min(n0 + 255, N_NODES - 1)];
    int range = gmax - gmin + 1;
    if (range <= 64) {
        for (int t = threadIdx.x; t < range * 16; t += 256) acc[t] = 0.0f;
        __syncthreads();
        if (n < N_NODES) {
            int g = batch[n] - gmin;
            float* dst = &acc[g * 16];
            #pragma unroll
            for (int k = 0; k < 16; k++) atomicAdd(&dst[k], v[k]);
        }
        __syncthreads();
        for (int t = threadIdx.x; t < range * 16; t += 256) {
            float w = acc[t];
            if (w != 0.0f) atomicAdd(&gsum[(size_t)gmin * 16 + t], w);
        }
    } else {
        if (n < N_NODES) {
            int g = batch[n];
            float* dst = gsum + (size_t)g * 16;
            #pragma unroll
            for (int k = 0; k < 16; k++) atomicAdd(&dst[k], v[k]);
        }
    }
}

// ---------- head ----------
__global__ __launch_bounds__(512) void head_kernel(
    const float* __restrict__ gsum,
    const float* __restrict__ fc1w, const float* __restrict__ fc1b,
    const float* __restrict__ gamma, const float* __restrict__ beta,
    const float* __restrict__ fc2w, const float* __restrict__ fc2b,
    float* __restrict__ out)
{
    __shared__ float ssum[D5], ssq[D5], smu[D5], sistd[D5];
    int g = threadIdx.x;
    if (g < D5) { ssum[g] = 0.0f; ssq[g] = 0.0f; }
    __syncthreads();

    const float* src = gsum + (size_t)g * 16;
    float inv = 1.0f / fmaxf(src[15], 1.0f);
    float u[D3];
    #pragma unroll
    for (int k = 0; k < D3; k++) u[k] = src[k] * inv;

    float h[D5];
    #pragma unroll
    for (int c = 0; c < D5; c++) h[c] = fc1b[c];
    #pragma unroll
    for (int k = 0; k < D3; k++) {
        float v = u[k];
        #pragma unroll
        for (int c = 0; c < D5; c++) h[c] = fmaf(v, fc1w[k * D5 + c], h[c]);
    }

    int lane = threadIdx.x & 63;
    #pragma unroll
    for (int c = 0; c < D5; c++) {
        float v = h[c];
        float v2 = v * v;
        #pragma unroll
        for (int off = 32; off >= 1; off >>= 1) {
            v  += __shfl_xor(v,  off);
            v2 += __shfl_xor(v2, off);
        }
        if (lane == 0) { atomicAdd(&ssum[c], v); atomicAdd(&ssq[c], v2); }
    }
    __syncthreads();
    if (g < D5) {
        float mu = ssum[g] * (1.0f / NUM_GRAPHS);
        float var = ssq[g] * (1.0f / NUM_GRAPHS) - mu * mu;
        smu[g] = mu;
        sistd[g] = rsqrtf(var + BN_EPS);
    }
    __syncthreads();

    float hn[D5];
    #pragma unroll
    for (int c = 0; c < D5; c++) {
        float v = gamma[c] * (h[c] - smu[c]) * sistd[c] + beta[c];
        hn[c] = fmaxf(v, 0.0f);
    }

    float lg[NCLS];
    #pragma unroll
    for (int j = 0; j < NCLS; j++) lg[j] = fc2b[j];
    #pragma unroll
    for (int c = 0; c < D5; c++) {
        float v = hn[c];
        #pragma unroll
        for (int j = 0; j < NCLS; j++) lg[j] = fmaf(v, fc2w[c * NCLS + j], lg[j]);
    }

    float m = lg[0];
    #pragma unroll
    for (int j = 1; j < NCLS; j++) m = fmaxf(m, lg[j]);
    float se = 0.0f;
    #pragma unroll
    for (int j = 0; j < NCLS; j++) se += expf(lg[j] - m);
    float lse = logf(se);
    #pragma unroll
    for (int j = 0; j < NCLS; j++) out[g * NCLS + j] = lg[j] - m - lse;
}

extern "C" void kernel_launch(void* const* d_in, const int* in_sizes, int n_in,
                              void* d_out, int out_size, void* d_ws, size_t ws_size,
                              hipStream_t stream) {
    const float* x         = (const float*)d_in[0];
    const float* edge_attr = (const float*)d_in[1];
    const float* ew1  = (const float*)d_in[2];
    const float* eb1  = (const float*)d_in[3];
    const float* ew2  = (const float*)d_in[4];
    const float* eb2  = (const float*)d_in[5];
    const float* nw1  = (const float*)d_in[6];
    const float* nb1  = (const float*)d_in[7];
    const float* nw2  = (const float*)d_in[8];
    const float* nb2  = (const float*)d_in[9];
    const float* fc1w = (const float*)d_in[10];
    const float* fc1b = (const float*)d_in[11];
    const float* gamma= (const float*)d_in[12];
    const float* beta = (const float*)d_in[13];
    const float* fc2w = (const float*)d_in[14];
    const float* fc2b = (const float*)d_in[15];
    const int* edge_index = (const int*)d_in[16];
    const int* batch      = (const int*)d_in[17];

    // workspace layout
    char* p = (char*)d_ws;
    unsigned short* msgb = (unsigned short*)p; p += (size_t)N_EDGES * 16 * sizeof(unsigned short); // 51.2 MB
    int* counts  = (int*)p;            p += (size_t)N_NODES * sizeof(int);
    int* scanned = (int*)p;            p += (size_t)N_NODES * sizeof(int);
    int* cursor  = (int*)p;            p += (size_t)N_NODES * sizeof(int);
    int* bsums   = (int*)p;            p += 128 * sizeof(int);
    int* bofs    = (int*)p;            p += 128 * sizeof(int);
    ushort4* x4b = (ushort4*)p;        p += (size_t)N_NODES * sizeof(ushort4);     // 0.8 MB
    float* gsum  = (float*)p;          p += (size_t)NUM_GRAPHS * 16 * sizeof(float);
    unsigned short* wh = (unsigned short*)p; p += W_TOTAL * sizeof(unsigned short);
    unsigned short* wl = (unsigned short*)p; p += W_TOTAL * sizeof(unsigned short);

    hipMemsetAsync(counts, 0, (size_t)N_NODES * sizeof(int), stream);
    hipMemsetAsync(gsum, 0, (size_t)NUM_GRAPHS * 16 * sizeof(float), stream);

    int egrid = (N_EDGES + 255) / 256;
    int ngrid = (N_NODES + 255) / 256;

    prep_kernel<<<egrid, 256, 0, stream>>>(
        ew1, eb1, ew2, eb2, nw1, nb1, nw2, nb2, wh, wl,
        x, x4b, edge_index, counts);
    scan1_kernel<<<NBLK1, 1024, 0, stream>>>(counts, scanned, bsums);
    scan2_kernel<<<1, 128, 0, stream>>>(bsums, bofs);
    scan3_kernel<<<ngrid, 256, 0, stream>>>(scanned, bofs, cursor);
    edge_mfma_kernel<<<EDGE_BLOCKS, 256, 0, stream>>>(
        wh, wl, x4b, edge_attr, edge_index, cursor, msgb);
    gather_pool_kernel<<<ngrid, 256, 0, stream>>>(
        msgb, scanned, bofs, counts, batch, gsum);
    head_kernel<<<1, 512, 0, stream>>>(
        gsum, fc1w, fc1b, gamma, beta, fc2w, fc2b, (float*)d_out);
}

// Round 10
// 328.404 us; speedup vs baseline: 1.1363x; 1.0499x over previous
//
#include <hip/hip_runtime.h>
#include <hip/hip_bf16.h>
#include <math.h>

#define N_NODES    100000
#define N_EDGES    1600000
#define NUM_GRAPHS 512
#define D2 50
#define D3 15
#define D5 10
#define NCLS 6
#define BN_EPS 1e-5f

#define NBLK1 ((N_NODES + 1023) / 1024)   // 98 scan blocks

// global bf16 weight buffer layout (elements), padded/transposed
// ew1T [64 m][40 k] : k0-2 x_row, k3 bias, k4-6 x_col, k8-10 ea
// ew2T [16 m][72 k] : k0-49 h1, k50 bias
// nw1T [64 m][40 k] : k0-14 e2, k16-18 x_col, k19 bias
// nw2T [16 m][72 k] : k0-49 h2, k50 bias
#define W_EW1T 0
#define W_EW2T 2560
#define W_NW1T 3712
#define W_NW2T 6272
#define W_TOTAL 7680

#define EDGE_BLOCKS 2500
#define EDGE_WAVES  (EDGE_BLOCKS * 4)        // 10000
#define TILES32     (N_EDGES / 32)           // 50000
#define EDGE_ITERS  (TILES32 / EDGE_WAVES)   // 5

typedef __attribute__((ext_vector_type(8))) short short8;
typedef __attribute__((ext_vector_type(4))) float float4_;
union BU { unsigned u[4]; short8 s; };
union FU { unsigned u; float f; };

__device__ __forceinline__ unsigned short f2bf(float f) {
    __hip_bfloat16 h = __float2bfloat16(f);
    union { __hip_bfloat16 h; unsigned short u; } c; c.h = h; return c.u;
}
__device__ __forceinline__ unsigned int pkbf(float a, float b) {
    return (unsigned int)f2bf(a) | ((unsigned int)f2bf(b) << 16);
}
__device__ __forceinline__ unsigned bp(int s4, unsigned v) {
    return (unsigned)__builtin_amdgcn_ds_bpermute(s4, (int)v);
}
__device__ __forceinline__ float lo16(unsigned u) { FU c; c.u = u << 16; return c.f; }
__device__ __forceinline__ float hi16(unsigned u) { FU c; c.u = u & 0xFFFF0000u; return c.f; }

// ---------- fused prep: weight transpose (single bf16) + x pad + histogram ----------
__global__ __launch_bounds__(256) void prep_kernel(
    const float* __restrict__ ew1, const float* __restrict__ eb1,
    const float* __restrict__ ew2, const float* __restrict__ eb2,
    const float* __restrict__ nw1, const float* __restrict__ nb1,
    const float* __restrict__ nw2, const float* __restrict__ nb2,
    unsigned short* __restrict__ wh,
    const float* __restrict__ x, ushort4* __restrict__ x4b,
    const int* __restrict__ edge_index, int* __restrict__ counts)
{
    int gtid = blockIdx.x * 256 + threadIdx.x;
    int gsz = gridDim.x * 256;

    for (int i = gtid; i < W_TOTAL; i += gsz) {
        float v = 0.0f;
        if (i < W_EW2T) {
            int m = i / 40, k = i % 40;
            if (m < 50) {
                if (k < 3)                 v = ew1[k * 50 + m];
                else if (k == 3)           v = eb1[m];
                else if (k >= 4 && k < 7)  v = ew1[(k - 1) * 50 + m];
                else if (k >= 8 && k < 11) v = ew1[(k - 2) * 50 + m];
            }
        } else if (i < W_NW1T) {
            int j = i - W_EW2T; int m = j / 72, k = j % 72;
            if (m < 15) { if (k < 50) v = ew2[k * 15 + m]; else if (k == 50) v = eb2[m]; }
        } else if (i < W_NW2T) {
            int j = i - W_NW1T; int m = j / 40, k = j % 40;
            if (m < 50) {
                if (k < 15)                  v = nw1[(3 + k) * 50 + m];
                else if (k >= 16 && k < 19)  v = nw1[(k - 16) * 50 + m];
                else if (k == 19)            v = nb1[m];
            }
        } else if (i < 7424) {
            int j = i - W_NW2T; int m = j / 72, k = j % 72;
            if (m < 15) { if (k < 50) v = nw2[k * 15 + m]; else if (k == 50) v = nb2[m]; }
        }
        wh[i] = f2bf(v);
    }

    for (int n = gtid; n < N_NODES; n += gsz) {
        ushort4 v;
        v.x = f2bf(x[n * 3 + 0]); v.y = f2bf(x[n * 3 + 1]);
        v.z = f2bf(x[n * 3 + 2]); v.w = 0;
        x4b[n] = v;
    }

    for (int e = gtid; e < N_EDGES; e += gsz)
        atomicAdd(&counts[edge_index[e]], 1);
}

// ---------- single-pass CSR offsets: block scan + global-atomic block base ----------
// Block bases are assigned in arbitrary block order: still a valid disjoint
// partition of [0,N_EDGES) per node, which is all gather/edge need.
__global__ __launch_bounds__(1024) void scan_kernel(
    const int* __restrict__ counts, int* __restrict__ scanned,
    int* __restrict__ cursor, int* __restrict__ gctr)
{
    __shared__ int wsum[16], wofs[16];
    __shared__ int base;
    int i = blockIdx.x * 1024 + threadIdx.x;
    int lane = threadIdx.x & 63, wid = threadIdx.x >> 6;
    int v = (i < N_NODES) ? counts[i] : 0;
    int sc = v;
    #pragma unroll
    for (int off = 1; off < 64; off <<= 1) {
        int t = __shfl_up(sc, off);
        if (lane >= off) sc += t;
    }
    if (lane == 63) wsum[wid] = sc;
    __syncthreads();
    if (wid == 0) {
        int s = (lane < 16) ? wsum[lane] : 0;
        #pragma unroll
        for (int off = 1; off < 16; off <<= 1) {
            int t = __shfl_up(s, off);
            if (lane >= off) s += t;
        }
        if (lane < 16) wofs[lane] = s - wsum[lane];
    }
    __syncthreads();
    int incl = sc + wofs[wid];
    if (threadIdx.x == 1023) base = atomicAdd(gctr, incl);   // incl == block total
    __syncthreads();
    int start = base + incl - v;
    if (i < N_NODES) { scanned[i] = start; cursor[i] = start; }
}

// ---------- per-edge input fetch: each (quad,n) lane owns edge n's slice ----------
struct EIn { unsigned w0, w1, w2, w3, h0, h1; int pos; };

__device__ __forceinline__ EIn load_in(int ebase, int n, int quad,
    const int* __restrict__ edge_index, const ushort4* __restrict__ x4b,
    const float* __restrict__ edge_attr, int* __restrict__ cursor)
{
    EIn r; r.w0 = r.w1 = r.w2 = r.w3 = 0; r.h0 = r.h1 = 0; r.pos = 0;
    int e = ebase + n;
    if (quad == 0) {
        int row = edge_index[e];
        int col = edge_index[N_EDGES + e];
        ushort4 xr = x4b[row];
        ushort4 xc = x4b[col];
        r.w0 = (unsigned)xr.x | ((unsigned)xr.y << 16);   // k0,k1 = x_row
        r.w1 = (unsigned)xr.z | (0x3F80u << 16);          // k2, k3=bias
        r.w2 = (unsigned)xc.x | ((unsigned)xc.y << 16);   // k4,k5 = x_col
        r.w3 = (unsigned)xc.z;                            // k6, k7=0
        r.pos = atomicAdd(&cursor[row], 1);
    } else if (quad == 1) {
        r.w0 = pkbf(edge_attr[e * 3 + 0], edge_attr[e * 3 + 1]);  // k8,k9
        r.w1 = (unsigned)f2bf(edge_attr[e * 3 + 2]);              // k10, k11=0
    } else if (quad == 2) {
        int col = edge_index[N_EDGES + e];
        ushort4 xc = x4b[col];
        r.h0 = (unsigned)xc.x | ((unsigned)xc.y << 16);   // nodeMLP k16,k17
        r.h1 = (unsigned)xc.z | (0x3F80u << 16);          // k18, k19=bias
    }
    return r;
}

// 64-ch C output (4 blocks, packed pairs U[4][2]) -> two K=32 B fragments
__device__ __forceinline__ void perm64(const unsigned U[4][2], int s0, int s1, bool hi,
                                       short8& Bc0, short8& Bc1)
{
    BU b0, b1;
    {
        unsigned a0 = bp(s0, U[0][0]), a1 = bp(s0, U[1][0]);
        unsigned a2 = bp(s0, U[0][1]), a3 = bp(s0, U[1][1]);
        unsigned a4 = bp(s1, U[0][0]), a5 = bp(s1, U[1][0]);
        unsigned a6 = bp(s1, U[0][1]), a7 = bp(s1, U[1][1]);
        b0.u[0] = hi ? a1 : a0;
        b0.u[1] = hi ? a3 : a2;
        b0.u[2] = hi ? a5 : a4;
        b0.u[3] = hi ? a7 : a6;
    }
    {
        unsigned a0 = bp(s0, U[2][0]), a1 = bp(s0, U[3][0]);
        unsigned a2 = bp(s0, U[2][1]), a3 = bp(s0, U[3][1]);
        unsigned a4 = bp(s1, U[2][0]), a5 = bp(s1, U[3][0]);
        unsigned a6 = bp(s1, U[2][1]), a7 = bp(s1, U[3][1]);
        b1.u[0] = hi ? a1 : a0;
        b1.u[1] = hi ? a3 : a2;
        b1.u[2] = hi ? a5 : a4;
        b1.u[3] = hi ? a7 : a6;
    }
    Bc0 = b0.s; Bc1 = b1.s;
}

// 16-ch C output (packed U2[2]) + static x_col/bias part -> K=32 B fragment
__device__ __forceinline__ short8 perm16(const unsigned U2[2], int s0, int s1,
                                         int quad, unsigned h0, unsigned h1)
{
    BU d;
    d.u[0] = bp(s0, U2[0]);
    d.u[1] = bp(s0, U2[1]);
    d.u[2] = bp(s1, U2[0]);
    d.u[3] = bp(s1, U2[1]);
    if (quad == 2) { d.u[0] = h0; d.u[1] = h1; d.u[2] = 0; d.u[3] = 0; }
    else if (quad == 3) { d.u[0] = 0; d.u[1] = 0; d.u[2] = 0; d.u[3] = 0; }
    return d.s;
}

// ---------- MFMA edge MLP: single-bf16 weights (12 A-fragments = 48 regs),
// 24 MFMAs/tile-pair, chain depth 1 per 64-ch layer. ----------
__global__ __launch_bounds__(256) void edge_mfma_kernel(
    const unsigned short* __restrict__ wh_g,
    const ushort4* __restrict__ x4b, const float* __restrict__ edge_attr,
    const int* __restrict__ edge_index,
    int* __restrict__ cursor, unsigned short* __restrict__ msgb)
{
    int tid = threadIdx.x, wave = tid >> 6, lane = tid & 63;
    int n = lane & 15, quad = lane >> 4;

    // A-fragments (weights) -> registers, once per wave
    short8 A1[4], A3[4];
    #pragma unroll
    for (int t4 = 0; t4 < 4; t4++) {
        A1[t4] = *(const short8*)(wh_g + W_EW1T + (t4 * 16 + n) * 40 + quad * 8);
        A3[t4] = *(const short8*)(wh_g + W_NW1T + (t4 * 16 + n) * 40 + quad * 8);
    }
    short8 A2[2], A4[2];
    #pragma unroll
    for (int kc = 0; kc < 2; kc++) {
        A2[kc] = *(const short8*)(wh_g + W_EW2T + n * 72 + kc * 32 + quad * 8);
        A4[kc] = *(const short8*)(wh_g + W_NW2T + n * 72 + kc * 32 + quad * 8);
    }

    int s0 = ((quad & 1) * 32 + n) * 4;   // byte index for bpermute (lane*4)
    int s1 = s0 + 64;
    bool hi = (quad & 2) != 0;

    int t = blockIdx.x * 4 + wave;
    EIn cur0 = load_in(t * 32,      n, quad, edge_index, x4b, edge_attr, cursor);
    EIn cur1 = load_in(t * 32 + 16, n, quad, edge_index, x4b, edge_attr, cursor);

    for (int it = 0; it < EDGE_ITERS; it++) {
        int p0 = __shfl(cur0.pos, n);
        int p1 = __shfl(cur1.pos, n);

        int tn = t + EDGE_WAVES;
        EIn nx0, nx1;
        nx0.w0 = nx0.w1 = nx0.w2 = nx0.w3 = nx0.h0 = nx0.h1 = 0; nx0.pos = 0;
        nx1 = nx0;
        if (it + 1 < EDGE_ITERS) {
            nx0 = load_in(tn * 32,      n, quad, edge_index, x4b, edge_attr, cursor);
            nx1 = load_in(tn * 32 + 16, n, quad, edge_index, x4b, edge_attr, cursor);
        }

        // B1 direct from registers
        BU t0, t1;
        t0.u[0] = cur0.w0; t0.u[1] = cur0.w1; t0.u[2] = cur0.w2; t0.u[3] = cur0.w3;
        t1.u[0] = cur1.w0; t1.u[1] = cur1.w1; t1.u[2] = cur1.w2; t1.u[3] = cur1.w3;
        short8 B1a = t0.s, B1b = t1.s;

        // ---- layer 1: [64ch] x K=32 ----
        unsigned U1a[4][2], U1b[4][2];
        #pragma unroll
        for (int t4 = 0; t4 < 4; t4++) {
            float4_ za = {0.f, 0.f, 0.f, 0.f}, zb = {0.f, 0.f, 0.f, 0.f};
            za = __builtin_amdgcn_mfma_f32_16x16x32_bf16(A1[t4], B1a, za, 0, 0, 0);
            zb = __builtin_amdgcn_mfma_f32_16x16x32_bf16(A1[t4], B1b, zb, 0, 0, 0);
            U1a[t4][0] = pkbf(fmaxf(za[0], 0.f), fmaxf(za[1], 0.f));
            U1a[t4][1] = pkbf(fmaxf(za[2], 0.f), fmaxf(za[3], 0.f));
            U1b[t4][0] = pkbf(fmaxf(zb[0], 0.f), fmaxf(zb[1], 0.f));
            U1b[t4][1] = pkbf(fmaxf(zb[2], 0.f), fmaxf(zb[3], 0.f));
        }

        short8 B2a0, B2a1, B2b0, B2b1;
        perm64(U1a, s0, s1, hi, B2a0, B2a1);
        perm64(U1b, s0, s1, hi, B2b0, B2b1);
        // bias=1 at k=50: kc=1, quad_b=2, j=2 -> low half of uint[1]
        if (quad == 2) {
            BU fa, fb; fa.s = B2a1; fb.s = B2b1;
            fa.u[1] = (fa.u[1] & 0xFFFF0000u) | 0x3F80u;
            fb.u[1] = (fb.u[1] & 0xFFFF0000u) | 0x3F80u;
            B2a1 = fa.s; B2b1 = fb.s;
        }

        // ---- layer 2: [16ch] x K=64 ----
        float4_ a2a = {0.f, 0.f, 0.f, 0.f}, a2b = {0.f, 0.f, 0.f, 0.f};
        a2a = __builtin_amdgcn_mfma_f32_16x16x32_bf16(A2[0], B2a0, a2a, 0, 0, 0);
        a2b = __builtin_amdgcn_mfma_f32_16x16x32_bf16(A2[0], B2b0, a2b, 0, 0, 0);
        a2a = __builtin_amdgcn_mfma_f32_16x16x32_bf16(A2[1], B2a1, a2a, 0, 0, 0);
        a2b = __builtin_amdgcn_mfma_f32_16x16x32_bf16(A2[1], B2b1, a2b, 0, 0, 0);

        unsigned U2a[2] = { pkbf(a2a[0], a2a[1]), pkbf(a2a[2], a2a[3]) };
        unsigned U2b[2] = { pkbf(a2b[0], a2b[1]), pkbf(a2b[2], a2b[3]) };

        short8 B3a = perm16(U2a, s0, s1, quad, cur0.h0, cur0.h1);
        short8 B3b = perm16(U2b, s0, s1, quad, cur1.h0, cur1.h1);

        // ---- layer 3: [64ch] x K=32 ----
        unsigned U3a[4][2], U3b[4][2];
        #pragma unroll
        for (int t4 = 0; t4 < 4; t4++) {
            float4_ za = {0.f, 0.f, 0.f, 0.f}, zb = {0.f, 0.f, 0.f, 0.f};
            za = __builtin_amdgcn_mfma_f32_16x16x32_bf16(A3[t4], B3a, za, 0, 0, 0);
            zb = __builtin_amdgcn_mfma_f32_16x16x32_bf16(A3[t4], B3b, zb, 0, 0, 0);
            U3a[t4][0] = pkbf(fmaxf(za[0], 0.f), fmaxf(za[1], 0.f));
            U3a[t4][1] = pkbf(fmaxf(za[2], 0.f), fmaxf(za[3], 0.f));
            U3b[t4][0] = pkbf(fmaxf(zb[0], 0.f), fmaxf(zb[1], 0.f));
            U3b[t4][1] = pkbf(fmaxf(zb[2], 0.f), fmaxf(zb[3], 0.f));
        }

        short8 B4a0, B4a1, B4b0, B4b1;
        perm64(U3a, s0, s1, hi, B4a0, B4a1);
        perm64(U3b, s0, s1, hi, B4b0, B4b1);
        if (quad == 2) {
            BU fa, fb; fa.s = B4a1; fb.s = B4b1;
            fa.u[1] = (fa.u[1] & 0xFFFF0000u) | 0x3F80u;
            fb.u[1] = (fb.u[1] & 0xFFFF0000u) | 0x3F80u;
            B4a1 = fa.s; B4b1 = fb.s;
        }

        // ---- layer 4: [16ch] x K=64 ----
        float4_ ma = {0.f, 0.f, 0.f, 0.f}, mb = {0.f, 0.f, 0.f, 0.f};
        ma = __builtin_amdgcn_mfma_f32_16x16x32_bf16(A4[0], B4a0, ma, 0, 0, 0);
        mb = __builtin_amdgcn_mfma_f32_16x16x32_bf16(A4[0], B4b0, mb, 0, 0, 0);
        ma = __builtin_amdgcn_mfma_f32_16x16x32_bf16(A4[1], B4a1, ma, 0, 0, 0);
        mb = __builtin_amdgcn_mfma_f32_16x16x32_bf16(A4[1], B4b1, mb, 0, 0, 0);

        // bf16 msg: 16 ch * 2B = 32 B/edge; lane writes its 4 channels (8 B)
        uint2 pa, pb;
        pa.x = pkbf(ma[0], ma[1]); pa.y = pkbf(ma[2], ma[3]);
        pb.x = pkbf(mb[0], mb[1]); pb.y = pkbf(mb[2], mb[3]);
        *(uint2*)(msgb + (size_t)p0 * 16 + quad * 4) = pa;
        *(uint2*)(msgb + (size_t)p1 * 16 + quad * 4) = pb;

        cur0 = nx0; cur1 = nx1; t = tn;
    }
}

// ---------- fused gather (CSR segment mean) + pool (sorted batch) ----------
__global__ __launch_bounds__(256) void gather_pool_kernel(
    const unsigned short* __restrict__ msgb, const int* __restrict__ scanned,
    const int* __restrict__ counts, const int* __restrict__ batch,
    float* __restrict__ gsum)
{
    __shared__ float acc[64 * 16];
    int n0 = blockIdx.x * 256;
    int n = n0 + threadIdx.x;

    float v[16];
    #pragma unroll
    for (int k = 0; k < 16; k++) v[k] = 0.0f;
    if (n < N_NODES) {
        int start = scanned[n];
        int deg = counts[n];
        for (int j = 0; j < deg; j++) {
            const uint4* mp = (const uint4*)(msgb + (size_t)(start + j) * 16);
            uint4 qa = mp[0], qb = mp[1];
            v[0]  += lo16(qa.x); v[1]  += hi16(qa.x);
            v[2]  += lo16(qa.y); v[3]  += hi16(qa.y);
            v[4]  += lo16(qa.z); v[5]  += hi16(qa.z);
            v[6]  += lo16(qa.w); v[7]  += hi16(qa.w);
            v[8]  += lo16(qb.x); v[9]  += hi16(qb.x);
            v[10] += lo16(qb.y); v[11] += hi16(qb.y);
            v[12] += lo16(qb.z); v[13] += hi16(qb.z);
            v[14] += lo16(qb.w);
        }
        float inv = 1.0f / fmaxf((float)deg, 1.0f);
        #pragma unroll
        for (int k = 0; k < 15; k++) v[k] *= inv;
        v[15] = 1.0f;   // node count
    }

    int gmin = batch[n0];
    int gmax = batch[min(n0 + 255, N_NODES - 1)];
    int range = gmax - gmin + 1;
    if (range <= 64) {
        for (int t = threadIdx.x; t < range * 16; t += 256) acc[t] = 0.0f;
        __syncthreads();
        if (n < N_NODES) {
            int g = batch[n] - gmin;
            float* dst = &acc[g * 16];
            #pragma unroll
            for (int k = 0; k < 16; k++) atomicAdd(&dst[k], v[k]);
        }
        __syncthreads();
        for (int t = threadIdx.x; t < range * 16; t += 256) {
            float w = acc[t];
            if (w != 0.0f) atomicAdd(&gsum[(size_t)gmin * 16 + t], w);
        }
    } else {
        if (n < N_NODES) {
            int g = batch[n];
            float* dst = gsum + (size_t)g * 16;
            #pragma unroll
            for (int k = 0; k < 16; k++) atomicAdd(&dst[k], v[k]);
        }
    }
}

// ---------- head ----------
__global__ __launch_bounds__(512) void head_kernel(
    const float* __restrict__ gsum,
    const float* __restrict__ fc1w, const float* __restrict__ fc1b,
    const float* __restrict__ gamma, const float* __restrict__ beta,
    const float* __restrict__ fc2w, const float* __restrict__ fc2b,
    float* __restrict__ out)
{
    __shared__ float ssum[D5], ssq[D5], smu[D5], sistd[D5];
    int g = threadIdx.x;
    if (g < D5) { ssum[g] = 0.0f; ssq[g] = 0.0f; }
    __syncthreads();

    const float* src = gsum + (size_t)g * 16;
    float inv = 1.0f / fmaxf(src[15], 1.0f);
    float u[D3];
    #pragma unroll
    for (int k = 0; k < D3; k++) u[k] = src[k] * inv;

    float h[D5];
    #pragma unroll
    for (int c = 0; c < D5; c++) h[c] = fc1b[c];
    #pragma unroll
    for (int k = 0; k < D3; k++) {
        float v = u[k];
        #pragma unroll
        for (int c = 0; c < D5; c++) h[c] = fmaf(v, fc1w[k * D5 + c], h[c]);
    }

    int lane = threadIdx.x & 63;
    #pragma unroll
    for (int c = 0; c < D5; c++) {
        float v = h[c];
        float v2 = v * v;
        #pragma unroll
        for (int off = 32; off >= 1; off >>= 1) {
            v  += __shfl_xor(v,  off);
            v2 += __shfl_xor(v2, off);
        }
        if (lane == 0) { atomicAdd(&ssum[c], v); atomicAdd(&ssq[c], v2); }
    }
    __syncthreads();
    if (g < D5) {
        float mu = ssum[g] * (1.0f / NUM_GRAPHS);
        float var = ssq[g] * (1.0f / NUM_GRAPHS) - mu * mu;
        smu[g] = mu;
        sistd[g] = rsqrtf(var + BN_EPS);
    }
    __syncthreads();

    float hn[D5];
    #pragma unroll
    for (int c = 0; c < D5; c++) {
        float v = gamma[c] * (h[c] - smu[c]) * sistd[c] + beta[c];
        hn[c] = fmaxf(v, 0.0f);
    }

    float lg[NCLS];
    #pragma unroll
    for (int j = 0; j < NCLS; j++) lg[j] = fc2b[j];
    #pragma unroll
    for (int c = 0; c < D5; c++) {
        float v = hn[c];
        #pragma unroll
        for (int j = 0; j < NCLS; j++) lg[j] = fmaf(v, fc2w[c * NCLS + j], lg[j]);
    }

    float m = lg[0];
    #pragma unroll
    for (int j = 1; j < NCLS; j++) m = fmaxf(m, lg[j]);
    float se = 0.0f;
    #pragma unroll
    for (int j = 0; j < NCLS; j++) se += expf(lg[j] - m);
    float lse = logf(se);
    #pragma unroll
    for (int j = 0; j < NCLS; j++) out[g * NCLS + j] = lg[j] - m - lse;
}

extern "C" void kernel_launch(void* const* d_in, const int* in_sizes, int n_in,
                              void* d_out, int out_size, void* d_ws, size_t ws_size,
                              hipStream_t stream) {
    const float* x         = (const float*)d_in[0];
    const float* edge_attr = (const float*)d_in[1];
    const float* ew1  = (const float*)d_in[2];
    const float* eb1  = (const float*)d_in[3];
    const float* ew2  = (const float*)d_in[4];
    const float* eb2  = (const float*)d_in[5];
    const float* nw1  = (const float*)d_in[6];
    const float* nb1  = (const float*)d_in[7];
    const float* nw2  = (const float*)d_in[8];
    const float* nb2  = (const float*)d_in[9];
    const float* fc1w = (const float*)d_in[10];
    const float* fc1b = (const float*)d_in[11];
    const float* gamma= (const float*)d_in[12];
    const float* beta = (const float*)d_in[13];
    const float* fc2w = (const float*)d_in[14];
    const float* fc2b = (const float*)d_in[15];
    const int* edge_index = (const int*)d_in[16];
    const int* batch      = (const int*)d_in[17];

    // workspace layout
    char* p = (char*)d_ws;
    unsigned short* msgb = (unsigned short*)p; p += (size_t)N_EDGES * 16 * sizeof(unsigned short); // 51.2 MB
    int* counts  = (int*)p;            p += (size_t)N_NODES * sizeof(int);
    int* gctr    = (int*)p;            p += sizeof(int);                    // zeroed with counts
    int* scanned = (int*)p;            p += (size_t)N_NODES * sizeof(int);
    int* cursor  = (int*)p;            p += (size_t)N_NODES * sizeof(int);
    ushort4* x4b = (ushort4*)p;        p += (size_t)N_NODES * sizeof(ushort4);     // 0.8 MB
    float* gsum  = (float*)p;          p += (size_t)NUM_GRAPHS * 16 * sizeof(float);
    unsigned short* wh = (unsigned short*)p; p += W_TOTAL * sizeof(unsigned short);

    hipMemsetAsync(counts, 0, (size_t)(N_NODES + 1) * sizeof(int), stream);  // counts + gctr
    hipMemsetAsync(gsum, 0, (size_t)NUM_GRAPHS * 16 * sizeof(float), stream);

    int egrid = (N_EDGES + 255) / 256;
    int ngrid = (N_NODES + 255) / 256;

    prep_kernel<<<egrid, 256, 0, stream>>>(
        ew1, eb1, ew2, eb2, nw1, nb1, nw2, nb2, wh,
        x, x4b, edge_index, counts);
    scan_kernel<<<NBLK1, 1024, 0, stream>>>(counts, scanned, cursor, gctr);
    edge_mfma_kernel<<<EDGE_BLOCKS, 256, 0, stream>>>(
        wh, x4b, edge_attr, edge_index, cursor, msgb);
    gather_pool_kernel<<<ngrid, 256, 0, stream>>>(
        msgb, scanned, counts, batch, gsum);
    head_kernel<<<1, 512, 0, stream>>>(
        gsum, fc1w, fc1b, gamma, beta, fc2w, fc2b, (float*)d_out);
}

// Round 11
// 325.558 us; speedup vs baseline: 1.1462x; 1.0087x over previous
//
#include <hip/hip_runtime.h>
#include <hip/hip_bf16.h>
#include <math.h>

#define N_NODES    100000
#define N_EDGES    1600000
#define NUM_GRAPHS 512
#define D2 50
#define D3 15
#define D5 10
#define NCLS 6
#define BN_EPS 1e-5f

#define NBLK1 ((N_NODES + 1023) / 1024)   // 98 scan blocks

// global bf16 weight buffer layout (elements), padded/transposed
// ew1T [64 m][40 k] : k0-2 x_row, k3 bias, k4-6 x_col, k8-10 ea
// ew2T [16 m][72 k] : k0-49 h1, k50 bias
// nw1T [64 m][40 k] : k0-14 e2, k16-18 x_col, k19 bias
// nw2T [16 m][72 k] : k0-49 h2, k50 bias
#define W_EW1T 0
#define W_EW2T 2560
#define W_NW1T 3712
#define W_NW2T 6272
#define W_TOTAL 7680

#define EDGE_BLOCKS 2500
#define EDGE_WAVES  (EDGE_BLOCKS * 4)        // 10000
#define TILES32     (N_EDGES / 32)           // 50000
#define EDGE_ITERS  (TILES32 / EDGE_WAVES)   // 5

typedef __attribute__((ext_vector_type(8))) short short8;
typedef __attribute__((ext_vector_type(4))) float float4_;
union BU { unsigned u[4]; short8 s; };
union FU { unsigned u; float f; };

__device__ __forceinline__ unsigned short f2bf(float f) {
    __hip_bfloat16 h = __float2bfloat16(f);
    union { __hip_bfloat16 h; unsigned short u; } c; c.h = h; return c.u;
}
// gfx950 native packed f32->bf16 (RNE): one instruction instead of ~16.
__device__ __forceinline__ unsigned pkbf(float a, float b) {
    unsigned r;
    asm("v_cvt_pk_bf16_f32 %0, %1, %2" : "=v"(r) : "v"(a), "v"(b));
    return r;
}
__device__ __forceinline__ unsigned bp(int s4, unsigned v) {
    return (unsigned)__builtin_amdgcn_ds_bpermute(s4, (int)v);
}
__device__ __forceinline__ float lo16(unsigned u) { FU c; c.u = u << 16; return c.f; }
__device__ __forceinline__ float hi16(unsigned u) { FU c; c.u = u & 0xFFFF0000u; return c.f; }

// ---------- fused prep: weight transpose (single bf16) + x pad + histogram ----------
__global__ __launch_bounds__(256) void prep_kernel(
    const float* __restrict__ ew1, const float* __restrict__ eb1,
    const float* __restrict__ ew2, const float* __restrict__ eb2,
    const float* __restrict__ nw1, const float* __restrict__ nb1,
    const float* __restrict__ nw2, const float* __restrict__ nb2,
    unsigned short* __restrict__ wh,
    const float* __restrict__ x, ushort4* __restrict__ x4b,
    const int* __restrict__ edge_index, int* __restrict__ counts)
{
    int gtid = blockIdx.x * 256 + threadIdx.x;
    int gsz = gridDim.x * 256;

    for (int i = gtid; i < W_TOTAL; i += gsz) {
        float v = 0.0f;
        if (i < W_EW2T) {
            int m = i / 40, k = i % 40;
            if (m < 50) {
                if (k < 3)                 v = ew1[k * 50 + m];
                else if (k == 3)           v = eb1[m];
                else if (k >= 4 && k < 7)  v = ew1[(k - 1) * 50 + m];
                else if (k >= 8 && k < 11) v = ew1[(k - 2) * 50 + m];
            }
        } else if (i < W_NW1T) {
            int j = i - W_EW2T; int m = j / 72, k = j % 72;
            if (m < 15) { if (k < 50) v = ew2[k * 15 + m]; else if (k == 50) v = eb2[m]; }
        } else if (i < W_NW2T) {
            int j = i - W_NW1T; int m = j / 40, k = j % 40;
            if (m < 50) {
                if (k < 15)                  v = nw1[(3 + k) * 50 + m];
                else if (k >= 16 && k < 19)  v = nw1[(k - 16) * 50 + m];
                else if (k == 19)            v = nb1[m];
            }
        } else if (i < 7424) {
            int j = i - W_NW2T; int m = j / 72, k = j % 72;
            if (m < 15) { if (k < 50) v = nw2[k * 15 + m]; else if (k == 50) v = nb2[m]; }
        }
        wh[i] = f2bf(v);
    }

    for (int n = gtid; n < N_NODES; n += gsz) {
        ushort4 v;
        v.x = f2bf(x[n * 3 + 0]); v.y = f2bf(x[n * 3 + 1]);
        v.z = f2bf(x[n * 3 + 2]); v.w = 0;
        x4b[n] = v;
    }

    for (int e = gtid; e < N_EDGES; e += gsz)
        atomicAdd(&counts[edge_index[e]], 1);
}

// ---------- single-pass CSR offsets: block scan + global-atomic block base ----------
__global__ __launch_bounds__(1024) void scan_kernel(
    const int* __restrict__ counts, int* __restrict__ scanned,
    int* __restrict__ cursor, int* __restrict__ gctr)
{
    __shared__ int wsum[16], wofs[16];
    __shared__ int base;
    int i = blockIdx.x * 1024 + threadIdx.x;
    int lane = threadIdx.x & 63, wid = threadIdx.x >> 6;
    int v = (i < N_NODES) ? counts[i] : 0;
    int sc = v;
    #pragma unroll
    for (int off = 1; off < 64; off <<= 1) {
        int t = __shfl_up(sc, off);
        if (lane >= off) sc += t;
    }
    if (lane == 63) wsum[wid] = sc;
    __syncthreads();
    if (wid == 0) {
        int s = (lane < 16) ? wsum[lane] : 0;
        #pragma unroll
        for (int off = 1; off < 16; off <<= 1) {
            int t = __shfl_up(s, off);
            if (lane >= off) s += t;
        }
        if (lane < 16) wofs[lane] = s - wsum[lane];
    }
    __syncthreads();
    int incl = sc + wofs[wid];
    if (threadIdx.x == 1023) base = atomicAdd(gctr, incl);   // incl == block total
    __syncthreads();
    int start = base + incl - v;
    if (i < N_NODES) { scanned[i] = start; cursor[i] = start; }
}

// ---------- per-edge input fetch: each (quad,n) lane owns edge n's slice ----------
struct EIn { unsigned w0, w1, w2, w3, h0, h1; int pos; };

__device__ __forceinline__ EIn load_in(int ebase, int n, int quad,
    const int* __restrict__ edge_index, const ushort4* __restrict__ x4b,
    const float* __restrict__ edge_attr, int* __restrict__ cursor)
{
    EIn r; r.w0 = r.w1 = r.w2 = r.w3 = 0; r.h0 = r.h1 = 0; r.pos = 0;
    int e = ebase + n;
    if (quad == 0) {
        int row = edge_index[e];
        int col = edge_index[N_EDGES + e];
        ushort4 xr = x4b[row];
        ushort4 xc = x4b[col];
        r.w0 = (unsigned)xr.x | ((unsigned)xr.y << 16);   // k0,k1 = x_row
        r.w1 = (unsigned)xr.z | (0x3F80u << 16);          // k2, k3=bias
        r.w2 = (unsigned)xc.x | ((unsigned)xc.y << 16);   // k4,k5 = x_col
        r.w3 = (unsigned)xc.z;                            // k6, k7=0
        r.pos = atomicAdd(&cursor[row], 1);
    } else if (quad == 1) {
        r.w0 = pkbf(edge_attr[e * 3 + 0], edge_attr[e * 3 + 1]);  // k8,k9
        r.w1 = pkbf(edge_attr[e * 3 + 2], 0.0f);                  // k10, k11=0
    } else if (quad == 2) {
        int col = edge_index[N_EDGES + e];
        ushort4 xc = x4b[col];
        r.h0 = (unsigned)xc.x | ((unsigned)xc.y << 16);   // nodeMLP k16,k17
        r.h1 = (unsigned)xc.z | (0x3F80u << 16);          // k18, k19=bias
    }
    return r;
}

// 64-ch C output (4 blocks, packed pairs U[4][2]) -> two K=32 B fragments
__device__ __forceinline__ void perm64(const unsigned U[4][2], int s0, int s1, bool hi,
                                       short8& Bc0, short8& Bc1)
{
    BU b0, b1;
    {
        unsigned a0 = bp(s0, U[0][0]), a1 = bp(s0, U[1][0]);
        unsigned a2 = bp(s0, U[0][1]), a3 = bp(s0, U[1][1]);
        unsigned a4 = bp(s1, U[0][0]), a5 = bp(s1, U[1][0]);
        unsigned a6 = bp(s1, U[0][1]), a7 = bp(s1, U[1][1]);
        b0.u[0] = hi ? a1 : a0;
        b0.u[1] = hi ? a3 : a2;
        b0.u[2] = hi ? a5 : a4;
        b0.u[3] = hi ? a7 : a6;
    }
    {
        unsigned a0 = bp(s0, U[2][0]), a1 = bp(s0, U[3][0]);
        unsigned a2 = bp(s0, U[2][1]), a3 = bp(s0, U[3][1]);
        unsigned a4 = bp(s1, U[2][0]), a5 = bp(s1, U[3][0]);
        unsigned a6 = bp(s1, U[2][1]), a7 = bp(s1, U[3][1]);
        b1.u[0] = hi ? a1 : a0;
        b1.u[1] = hi ? a3 : a2;
        b1.u[2] = hi ? a5 : a4;
        b1.u[3] = hi ? a7 : a6;
    }
    Bc0 = b0.s; Bc1 = b1.s;
}

// 16-ch C output (packed U2[2]) + static x_col/bias part -> K=32 B fragment
__device__ __forceinline__ short8 perm16(const unsigned U2[2], int s0, int s1,
                                         int quad, unsigned h0, unsigned h1)
{
    BU d;
    d.u[0] = bp(s0, U2[0]);
    d.u[1] = bp(s0, U2[1]);
    d.u[2] = bp(s1, U2[0]);
    d.u[3] = bp(s1, U2[1]);
    if (quad == 2) { d.u[0] = h0; d.u[1] = h1; d.u[2] = 0; d.u[3] = 0; }
    else if (quad == 3) { d.u[0] = 0; d.u[1] = 0; d.u[2] = 0; d.u[3] = 0; }
    return d.s;
}

// ---------- MFMA edge MLP: single-bf16 weights, native packed cvt ----------
__global__ __launch_bounds__(256) void edge_mfma_kernel(
    const unsigned short* __restrict__ wh_g,
    const ushort4* __restrict__ x4b, const float* __restrict__ edge_attr,
    const int* __restrict__ edge_index,
    int* __restrict__ cursor, unsigned short* __restrict__ msgb)
{
    int tid = threadIdx.x, wave = tid >> 6, lane = tid & 63;
    int n = lane & 15, quad = lane >> 4;

    // A-fragments (weights) -> registers, once per wave
    short8 A1[4], A3[4];
    #pragma unroll
    for (int t4 = 0; t4 < 4; t4++) {
        A1[t4] = *(const short8*)(wh_g + W_EW1T + (t4 * 16 + n) * 40 + quad * 8);
        A3[t4] = *(const short8*)(wh_g + W_NW1T + (t4 * 16 + n) * 40 + quad * 8);
    }
    short8 A2[2], A4[2];
    #pragma unroll
    for (int kc = 0; kc < 2; kc++) {
        A2[kc] = *(const short8*)(wh_g + W_EW2T + n * 72 + kc * 32 + quad * 8);
        A4[kc] = *(const short8*)(wh_g + W_NW2T + n * 72 + kc * 32 + quad * 8);
    }

    int s0 = ((quad & 1) * 32 + n) * 4;   // byte index for bpermute (lane*4)
    int s1 = s0 + 64;
    bool hi = (quad & 2) != 0;

    const float4_ Z0 = {0.f, 0.f, 0.f, 0.f};   // one zeroed acc quad, reused

    int t = blockIdx.x * 4 + wave;
    EIn cur0 = load_in(t * 32,      n, quad, edge_index, x4b, edge_attr, cursor);
    EIn cur1 = load_in(t * 32 + 16, n, quad, edge_index, x4b, edge_attr, cursor);

    for (int it = 0; it < EDGE_ITERS; it++) {
        int p0 = __shfl(cur0.pos, n);
        int p1 = __shfl(cur1.pos, n);

        int tn = t + EDGE_WAVES;
        EIn nx0, nx1;
        nx0.w0 = nx0.w1 = nx0.w2 = nx0.w3 = nx0.h0 = nx0.h1 = 0; nx0.pos = 0;
        nx1 = nx0;
        if (it + 1 < EDGE_ITERS) {
            nx0 = load_in(tn * 32,      n, quad, edge_index, x4b, edge_attr, cursor);
            nx1 = load_in(tn * 32 + 16, n, quad, edge_index, x4b, edge_attr, cursor);
        }

        // B1 direct from registers
        BU t0, t1;
        t0.u[0] = cur0.w0; t0.u[1] = cur0.w1; t0.u[2] = cur0.w2; t0.u[3] = cur0.w3;
        t1.u[0] = cur1.w0; t1.u[1] = cur1.w1; t1.u[2] = cur1.w2; t1.u[3] = cur1.w3;
        short8 B1a = t0.s, B1b = t1.s;

        // ---- layer 1: [64ch] x K=32 ----
        unsigned U1a[4][2], U1b[4][2];
        #pragma unroll
        for (int t4 = 0; t4 < 4; t4++) {
            float4_ za = __builtin_amdgcn_mfma_f32_16x16x32_bf16(A1[t4], B1a, Z0, 0, 0, 0);
            float4_ zb = __builtin_amdgcn_mfma_f32_16x16x32_bf16(A1[t4], B1b, Z0, 0, 0, 0);
            U1a[t4][0] = pkbf(fmaxf(za[0], 0.f), fmaxf(za[1], 0.f));
            U1a[t4][1] = pkbf(fmaxf(za[2], 0.f), fmaxf(za[3], 0.f));
            U1b[t4][0] = pkbf(fmaxf(zb[0], 0.f), fmaxf(zb[1], 0.f));
            U1b[t4][1] = pkbf(fmaxf(zb[2], 0.f), fmaxf(zb[3], 0.f));
        }

        short8 B2a0, B2a1, B2b0, B2b1;
        perm64(U1a, s0, s1, hi, B2a0, B2a1);
        perm64(U1b, s0, s1, hi, B2b0, B2b1);
        // bias=1 at k=50: kc=1, quad_b=2, j=2 -> low half of uint[1]
        if (quad == 2) {
            BU fa, fb; fa.s = B2a1; fb.s = B2b1;
            fa.u[1] = (fa.u[1] & 0xFFFF0000u) | 0x3F80u;
            fb.u[1] = (fb.u[1] & 0xFFFF0000u) | 0x3F80u;
            B2a1 = fa.s; B2b1 = fb.s;
        }

        // ---- layer 2: [16ch] x K=64 ----
        float4_ a2a = __builtin_amdgcn_mfma_f32_16x16x32_bf16(A2[0], B2a0, Z0, 0, 0, 0);
        float4_ a2b = __builtin_amdgcn_mfma_f32_16x16x32_bf16(A2[0], B2b0, Z0, 0, 0, 0);
        a2a = __builtin_amdgcn_mfma_f32_16x16x32_bf16(A2[1], B2a1, a2a, 0, 0, 0);
        a2b = __builtin_amdgcn_mfma_f32_16x16x32_bf16(A2[1], B2b1, a2b, 0, 0, 0);

        unsigned U2a[2] = { pkbf(a2a[0], a2a[1]), pkbf(a2a[2], a2a[3]) };
        unsigned U2b[2] = { pkbf(a2b[0], a2b[1]), pkbf(a2b[2], a2b[3]) };

        short8 B3a = perm16(U2a, s0, s1, quad, cur0.h0, cur0.h1);
        short8 B3b = perm16(U2b, s0, s1, quad, cur1.h0, cur1.h1);

        // ---- layer 3: [64ch] x K=32 ----
        unsigned U3a[4][2], U3b[4][2];
        #pragma unroll
        for (int t4 = 0; t4 < 4; t4++) {
            float4_ za = __builtin_amdgcn_mfma_f32_16x16x32_bf16(A3[t4], B3a, Z0, 0, 0, 0);
            float4_ zb = __builtin_amdgcn_mfma_f32_16x16x32_bf16(A3[t4], B3b, Z0, 0, 0, 0);
            U3a[t4][0] = pkbf(fmaxf(za[0], 0.f), fmaxf(za[1], 0.f));
            U3a[t4][1] = pkbf(fmaxf(za[2], 0.f), fmaxf(za[3], 0.f));
            U3b[t4][0] = pkbf(fmaxf(zb[0], 0.f), fmaxf(zb[1], 0.f));
            U3b[t4][1] = pkbf(fmaxf(zb[2], 0.f), fmaxf(zb[3], 0.f));
        }

        short8 B4a0, B4a1, B4b0, B4b1;
        perm64(U3a, s0, s1, hi, B4a0, B4a1);
        perm64(U3b, s0, s1, hi, B4b0, B4b1);
        if (quad == 2) {
            BU fa, fb; fa.s = B4a1; fb.s = B4b1;
            fa.u[1] = (fa.u[1] & 0xFFFF0000u) | 0x3F80u;
            fb.u[1] = (fb.u[1] & 0xFFFF0000u) | 0x3F80u;
            B4a1 = fa.s; B4b1 = fb.s;
        }

        // ---- layer 4: [16ch] x K=64 ----
        float4_ ma = __builtin_amdgcn_mfma_f32_16x16x32_bf16(A4[0], B4a0, Z0, 0, 0, 0);
        float4_ mb = __builtin_amdgcn_mfma_f32_16x16x32_bf16(A4[0], B4b0, Z0, 0, 0, 0);
        ma = __builtin_amdgcn_mfma_f32_16x16x32_bf16(A4[1], B4a1, ma, 0, 0, 0);
        mb = __builtin_amdgcn_mfma_f32_16x16x32_bf16(A4[1], B4b1, mb, 0, 0, 0);

        // bf16 msg: 16 ch * 2B = 32 B/edge; lane writes its 4 channels (8 B)
        uint2 pa, pb;
        pa.x = pkbf(ma[0], ma[1]); pa.y = pkbf(ma[2], ma[3]);
        pb.x = pkbf(mb[0], mb[1]); pb.y = pkbf(mb[2], mb[3]);
        *(uint2*)(msgb + (size_t)p0 * 16 + quad * 4) = pa;
        *(uint2*)(msgb + (size_t)p1 * 16 + quad * 4) = pb;

        cur0 = nx0; cur1 = nx1; t = tn;
    }
}

// ---------- fused gather (CSR segment mean) + pool (sorted batch) ----------
__global__ __launch_bounds__(256) void gather_pool_kernel(
    const unsigned short* __restrict__ msgb, const int* __restrict__ scanned,
    const int* __restrict__ counts, const int* __restrict__ batch,
    float* __restrict__ gsum)
{
    __shared__ float acc[64 * 16];
    int n0 = blockIdx.x * 256;
    int n = n0 + threadIdx.x;

    float v[16];
    #pragma unroll
    for (int k = 0; k < 16; k++) v[k] = 0.0f;
    if (n < N_NODES) {
        int start = scanned[n];
        int deg = counts[n];
        for (int j = 0; j < deg; j++) {
            const uint4* mp = (const uint4*)(msgb + (size_t)(start + j) * 16);
            uint4 qa = mp[0], qb = mp[1];
            v[0]  += lo16(qa.x); v[1]  += hi16(qa.x);
            v[2]  += lo16(qa.y); v[3]  += hi16(qa.y);
            v[4]  += lo16(qa.z); v[5]  += hi16(qa.z);
            v[6]  += lo16(qa.w); v[7]  += hi16(qa.w);
            v[8]  += lo16(qb.x); v[9]  += hi16(qb.x);
            v[10] += lo16(qb.y); v[11] += hi16(qb.y);
            v[12] += lo16(qb.z); v[13] += hi16(qb.z);
            v[14] += lo16(qb.w);
        }
        float inv = 1.0f / fmaxf((float)deg, 1.0f);
        #pragma unroll
        for (int k = 0; k < 15; k++) v[k] *= inv;
        v[15] = 1.0f;   // node count
    }

    int gmin = batch[n0];
    int gmax = batch[min(n0 + 255, N_NODES - 1)];
    int range = gmax - gmin + 1;
    if (range <= 64) {
        for (int t = threadIdx.x; t < range * 16; t += 256) acc[t] = 0.0f;
        __syncthreads();
        if (n < N_NODES) {
            int g = batch[n] - gmin;
            float* dst = &acc[g * 16];
            #pragma unroll
            for (int k = 0; k < 16; k++) atomicAdd(&dst[k], v[k]);
        }
        __syncthreads();
        for (int t = threadIdx.x; t < range * 16; t += 256) {
            float w = acc[t];
            if (w != 0.0f) atomicAdd(&gsum[(size_t)gmin * 16 + t], w);
        }
    } else {
        if (n < N_NODES) {
            int g = batch[n];
            float* dst = gsum + (size_t)g * 16;
            #pragma unroll
            for (int k = 0; k < 16; k++) atomicAdd(&dst[k], v[k]);
        }
    }
}

// ---------- head ----------
__global__ __launch_bounds__(512) void head_kernel(
    const float* __restrict__ gsum,
    const float* __restrict__ fc1w, const float* __restrict__ fc1b,
    const float* __restrict__ gamma, const float* __restrict__ beta,
    const float* __restrict__ fc2w, const float* __restrict__ fc2b,
    float* __restrict__ out)
{
    __shared__ float ssum[D5], ssq[D5], smu[D5], sistd[D5];
    int g = threadIdx.x;
    if (g < D5) { ssum[g] = 0.0f; ssq[g] = 0.0f; }
    __syncthreads();

    const float* src = gsum + (size_t)g * 16;
    float inv = 1.0f / fmaxf(src[15], 1.0f);
    float u[D3];
    #pragma unroll
    for (int k = 0; k < D3; k++) u[k] = src[k] * inv;

    float h[D5];
    #pragma unroll
    for (int c = 0; c < D5; c++) h[c] = fc1b[c];
    #pragma unroll
    for (int k = 0; k < D3; k++) {
        float v = u[k];
        #pragma unroll
        for (int c = 0; c < D5; c++) h[c] = fmaf(v, fc1w[k * D5 + c], h[c]);
    }

    int lane = threadIdx.x & 63;
    #pragma unroll
    for (int c = 0; c < D5; c++) {
        float v = h[c];
        float v2 = v * v;
        #pragma unroll
        for (int off = 32; off >= 1; off >>= 1) {
            v  += __shfl_xor(v,  off);
            v2 += __shfl_xor(v2, off);
        }
        if (lane == 0) { atomicAdd(&ssum[c], v); atomicAdd(&ssq[c], v2); }
    }
    __syncthreads();
    if (g < D5) {
        float mu = ssum[g] * (1.0f / NUM_GRAPHS);
        float var = ssq[g] * (1.0f / NUM_GRAPHS) - mu * mu;
        smu[g] = mu;
        sistd[g] = rsqrtf(var + BN_EPS);
    }
    __syncthreads();

    float hn[D5];
    #pragma unroll
    for (int c = 0; c < D5; c++) {
        float v = gamma[c] * (h[c] - smu[c]) * sistd[c] + beta[c];
        hn[c] = fmaxf(v, 0.0f);
    }

    float lg[NCLS];
    #pragma unroll
    for (int j = 0; j < NCLS; j++) lg[j] = fc2b[j];
    #pragma unroll
    for (int c = 0; c < D5; c++) {
        float v = hn[c];
        #pragma unroll
        for (int j = 0; j < NCLS; j++) lg[j] = fmaf(v, fc2w[c * NCLS + j], lg[j]);
    }

    float m = lg[0];
    #pragma unroll
    for (int j = 1; j < NCLS; j++) m = fmaxf(m, lg[j]);
    float se = 0.0f;
    #pragma unroll
    for (int j = 0; j < NCLS; j++) se += expf(lg[j] - m);
    float lse = logf(se);
    #pragma unroll
    for (int j = 0; j < NCLS; j++) out[g * NCLS + j] = lg[j] - m - lse;
}

extern "C" void kernel_launch(void* const* d_in, const int* in_sizes, int n_in,
                              void* d_out, int out_size, void* d_ws, size_t ws_size,
                              hipStream_t stream) {
    const float* x         = (const float*)d_in[0];
    const float* edge_attr = (const float*)d_in[1];
    const float* ew1  = (const float*)d_in[2];
    const float* eb1  = (const float*)d_in[3];
    const float* ew2  = (const float*)d_in[4];
    const float* eb2  = (const float*)d_in[5];
    const float* nw1  = (const float*)d_in[6];
    const float* nb1  = (const float*)d_in[7];
    const float* nw2  = (const float*)d_in[8];
    const float* nb2  = (const float*)d_in[9];
    const float* fc1w = (const float*)d_in[10];
    const float* fc1b = (const float*)d_in[11];
    const float* gamma= (const float*)d_in[12];
    const float* beta = (const float*)d_in[13];
    const float* fc2w = (const float*)d_in[14];
    const float* fc2b = (const float*)d_in[15];
    const int* edge_index = (const int*)d_in[16];
    const int* batch      = (const int*)d_in[17];

    // workspace layout
    char* p = (char*)d_ws;
    unsigned short* msgb = (unsigned short*)p; p += (size_t)N_EDGES * 16 * sizeof(unsigned short); // 51.2 MB
    int* counts  = (int*)p;            p += (size_t)N_NODES * sizeof(int);
    int* gctr    = (int*)p;            p += sizeof(int);                    // zeroed with counts
    int* scanned = (int*)p;            p += (size_t)N_NODES * sizeof(int);
    int* cursor  = (int*)p;            p += (size_t)N_NODES * sizeof(int);
    ushort4* x4b = (ushort4*)p;        p += (size_t)N_NODES * sizeof(ushort4);     // 0.8 MB
    float* gsum  = (float*)p;          p += (size_t)NUM_GRAPHS * 16 * sizeof(float);
    unsigned short* wh = (unsigned short*)p; p += W_TOTAL * sizeof(unsigned short);

    hipMemsetAsync(counts, 0, (size_t)(N_NODES + 1) * sizeof(int), stream);  // counts + gctr
    hipMemsetAsync(gsum, 0, (size_t)NUM_GRAPHS * 16 * sizeof(float), stream);

    int egrid = (N_EDGES + 255) / 256;
    int ngrid = (N_NODES + 255) / 256;

    prep_kernel<<<egrid, 256, 0, stream>>>(
        ew1, eb1, ew2, eb2, nw1, nb1, nw2, nb2, wh,
        x, x4b, edge_index, counts);
    scan_kernel<<<NBLK1, 1024, 0, stream>>>(counts, scanned, cursor, gctr);
    edge_mfma_kernel<<<EDGE_BLOCKS, 256, 0, stream>>>(
        wh, x4b, edge_attr, edge_index, cursor, msgb);
    gather_pool_kernel<<<ngrid, 256, 0, stream>>>(
        msgb, scanned, counts, batch, gsum);
    head_kernel<<<1, 512, 0, stream>>>(
        gsum, fc1w, fc1b, gamma, beta, fc2w, fc2b, (float*)d_out);
}

// Round 14
// 316.953 us; speedup vs baseline: 1.1773x; 1.0272x over previous
//
#include <hip/hip_runtime.h>
#include <hip/hip_bf16.h>
#include <math.h>

#define N_NODES    100000
#define N_EDGES    1600000
#define NUM_GRAPHS 512
#define D2 50
#define D3 15
#define D5 10
#define NCLS 6
#define BN_EPS 1e-5f

#define NBLK1 ((N_NODES + 1023) / 1024)   // 98 scan blocks

// global bf16 weight buffer layout (elements), padded/transposed
// ew1T [64 m][40 k] : k0-2 x_row, k3 bias, k4-6 x_col, k8-10 ea
// ew2T [16 m][72 k] : k0-49 h1, k50 bias
// nw1T [64 m][40 k] : k0-14 e2, k16-18 x_col, k19 bias
// nw2T [16 m][72 k] : k0-49 h2, k50 bias
#define W_EW1T 0
#define W_EW2T 2560
#define W_NW1T 3712
#define W_NW2T 6272
#define W_TOTAL 7680

#define EDGE_BLOCKS 2500
#define EDGE_WAVES  (EDGE_BLOCKS * 4)        // 10000
#define TILES32     (N_EDGES / 32)           // 50000
#define EDGE_ITERS  (TILES32 / EDGE_WAVES)   // 5

typedef __attribute__((ext_vector_type(8))) short short8;
typedef __attribute__((ext_vector_type(4))) float float4_;
union BU { unsigned u[4]; short8 s; };
union FU { unsigned u; float f; };

__device__ __forceinline__ unsigned short f2bf(float f) {
    __hip_bfloat16 h = __float2bfloat16(f);
    union { __hip_bfloat16 h; unsigned short u; } c; c.h = h; return c.u;
}
// gfx950 native packed f32->bf16 (RNE)
__device__ __forceinline__ unsigned pkbf(float a, float b) {
    unsigned r;
    asm("v_cvt_pk_bf16_f32 %0, %1, %2" : "=v"(r) : "v"(a), "v"(b));
    return r;
}
__device__ __forceinline__ unsigned bp(int s4, unsigned v) {
    return (unsigned)__builtin_amdgcn_ds_bpermute(s4, (int)v);
}
__device__ __forceinline__ float lo16(unsigned u) { FU c; c.u = u << 16; return c.f; }
__device__ __forceinline__ float hi16(unsigned u) { FU c; c.u = u & 0xFFFF0000u; return c.f; }

// ---------- fused prep: weight transpose (single bf16) + x pad + histogram ----------
// NOTE: histogram must stay SCALAR — int4 version failed correctness in
// R12/R13 (intermittent post-timing divergence); scalar passed R10/R11.
__global__ __launch_bounds__(256) void prep_kernel(
    const float* __restrict__ ew1, const float* __restrict__ eb1,
    const float* __restrict__ ew2, const float* __restrict__ eb2,
    const float* __restrict__ nw1, const float* __restrict__ nb1,
    const float* __restrict__ nw2, const float* __restrict__ nb2,
    unsigned short* __restrict__ wh,
    const float* __restrict__ x, ushort4* __restrict__ x4b,
    const int* __restrict__ edge_index, int* __restrict__ counts)
{
    int gtid = blockIdx.x * 256 + threadIdx.x;
    int gsz = gridDim.x * 256;

    for (int i = gtid; i < W_TOTAL; i += gsz) {
        float v = 0.0f;
        if (i < W_EW2T) {
            int m = i / 40, k = i % 40;
            if (m < 50) {
                if (k < 3)                 v = ew1[k * 50 + m];
                else if (k == 3)           v = eb1[m];
                else if (k >= 4 && k < 7)  v = ew1[(k - 1) * 50 + m];
                else if (k >= 8 && k < 11) v = ew1[(k - 2) * 50 + m];
            }
        } else if (i < W_NW1T) {
            int j = i - W_EW2T; int m = j / 72, k = j % 72;
            if (m < 15) { if (k < 50) v = ew2[k * 15 + m]; else if (k == 50) v = eb2[m]; }
        } else if (i < W_NW2T) {
            int j = i - W_NW1T; int m = j / 40, k = j % 40;
            if (m < 50) {
                if (k < 15)                  v = nw1[(3 + k) * 50 + m];
                else if (k >= 16 && k < 19)  v = nw1[(k - 16) * 50 + m];
                else if (k == 19)            v = nb1[m];
            }
        } else if (i < 7424) {
            int j = i - W_NW2T; int m = j / 72, k = j % 72;
            if (m < 15) { if (k < 50) v = nw2[k * 15 + m]; else if (k == 50) v = nb2[m]; }
        }
        wh[i] = f2bf(v);
    }

    for (int n = gtid; n < N_NODES; n += gsz) {
        ushort4 v;
        v.x = f2bf(x[n * 3 + 0]); v.y = f2bf(x[n * 3 + 1]);
        v.z = f2bf(x[n * 3 + 2]); v.w = 0;
        x4b[n] = v;
    }

    for (int e = gtid; e < N_EDGES; e += gsz)
        atomicAdd(&counts[edge_index[e]], 1);
}

// ---------- single-pass CSR offsets: block scan + global-atomic block base ----------
__global__ __launch_bounds__(1024) void scan_kernel(
    const int* __restrict__ counts, int* __restrict__ scanned,
    int* __restrict__ cursor, int* __restrict__ gctr)
{
    __shared__ int wsum[16], wofs[16];
    __shared__ int base;
    int i = blockIdx.x * 1024 + threadIdx.x;
    int lane = threadIdx.x & 63, wid = threadIdx.x >> 6;
    int v = (i < N_NODES) ? counts[i] : 0;
    int sc = v;
    #pragma unroll
    for (int off = 1; off < 64; off <<= 1) {
        int t = __shfl_up(sc, off);
        if (lane >= off) sc += t;
    }
    if (lane == 63) wsum[wid] = sc;
    __syncthreads();
    if (wid == 0) {
        int s = (lane < 16) ? wsum[lane] : 0;
        #pragma unroll
        for (int off = 1; off < 16; off <<= 1) {
            int t = __shfl_up(s, off);
            if (lane >= off) s += t;
        }
        if (lane < 16) wofs[lane] = s - wsum[lane];
    }
    __syncthreads();
    int incl = sc + wofs[wid];
    if (threadIdx.x == 1023) base = atomicAdd(gctr, incl);   // incl == block total
    __syncthreads();
    int start = base + incl - v;
    if (i < N_NODES) { scanned[i] = start; cursor[i] = start; }
}

// ---------- per-edge input fetch: each (quad,n) lane owns edge n's slice ----------
struct EIn { unsigned w0, w1, w2, w3, h0, h1; int pos; };

__device__ __forceinline__ EIn load_in(int ebase, int n, int quad,
    const int* __restrict__ edge_index, const ushort4* __restrict__ x4b,
    const float* __restrict__ edge_attr, int* __restrict__ cursor)
{
    EIn r; r.w0 = r.w1 = r.w2 = r.w3 = 0; r.h0 = r.h1 = 0; r.pos = 0;
    int e = ebase + n;
    if (quad == 0) {
        int row = edge_index[e];
        int col = edge_index[N_EDGES + e];
        ushort4 xr = x4b[row];
        ushort4 xc = x4b[col];
        r.w0 = (unsigned)xr.x | ((unsigned)xr.y << 16);   // k0,k1 = x_row
        r.w1 = (unsigned)xr.z | (0x3F80u << 16);          // k2, k3=bias
        r.w2 = (unsigned)xc.x | ((unsigned)xc.y << 16);   // k4,k5 = x_col
        r.w3 = (unsigned)xc.z;                            // k6, k7=0
        r.pos = atomicAdd(&cursor[row], 1);
    } else if (quad == 1) {
        r.w0 = pkbf(edge_attr[e * 3 + 0], edge_attr[e * 3 + 1]);  // k8,k9
        r.w1 = pkbf(edge_attr[e * 3 + 2], 0.0f);                  // k10, k11=0
    } else if (quad == 2) {
        int col = edge_index[N_EDGES + e];
        ushort4 xc = x4b[col];
        r.h0 = (unsigned)xc.x | ((unsigned)xc.y << 16);   // nodeMLP k16,k17
        r.h1 = (unsigned)xc.z | (0x3F80u << 16);          // k18, k19=bias
    }
    return r;
}

// 64-ch C output (4 blocks, packed pairs U[4][2]) -> two K=32 B fragments
__device__ __forceinline__ void perm64(const unsigned U[4][2], int s0, int s1, bool hi,
                                       short8& Bc0, short8& Bc1)
{
    BU b0, b1;
    {
        unsigned a0 = bp(s0, U[0][0]), a1 = bp(s0, U[1][0]);
        unsigned a2 = bp(s0, U[0][1]), a3 = bp(s0, U[1][1]);
        unsigned a4 = bp(s1, U[0][0]), a5 = bp(s1, U[1][0]);
        unsigned a6 = bp(s1, U[0][1]), a7 = bp(s1, U[1][1]);
        b0.u[0] = hi ? a1 : a0;
        b0.u[1] = hi ? a3 : a2;
        b0.u[2] = hi ? a5 : a4;
        b0.u[3] = hi ? a7 : a6;
    }
    {
        unsigned a0 = bp(s0, U[2][0]), a1 = bp(s0, U[3][0]);
        unsigned a2 = bp(s0, U[2][1]), a3 = bp(s0, U[3][1]);
        unsigned a4 = bp(s1, U[2][0]), a5 = bp(s1, U[3][0]);
        unsigned a6 = bp(s1, U[2][1]), a7 = bp(s1, U[3][1]);
        b1.u[0] = hi ? a1 : a0;
        b1.u[1] = hi ? a3 : a2;
        b1.u[2] = hi ? a5 : a4;
        b1.u[3] = hi ? a7 : a6;
    }
    Bc0 = b0.s; Bc1 = b1.s;
}

// 16-ch C output (packed U2[2]) + static x_col/bias part -> K=32 B fragment
__device__ __forceinline__ short8 perm16(const unsigned U2[2], int s0, int s1,
                                         int quad, unsigned h0, unsigned h1)
{
    BU d;
    d.u[0] = bp(s0, U2[0]);
    d.u[1] = bp(s0, U2[1]);
    d.u[2] = bp(s1, U2[0]);
    d.u[3] = bp(s1, U2[1]);
    if (quad == 2) { d.u[0] = h0; d.u[1] = h1; d.u[2] = 0; d.u[3] = 0; }
    else if (quad == 3) { d.u[0] = 0; d.u[1] = 0; d.u[2] = 0; d.u[3] = 0; }
    return d.s;
}

// ---------- MFMA edge MLP: single-bf16 weights, native packed cvt ----------
// NOTE: no min-waves __launch_bounds__ — (256,4) miscompiled (R12).
__global__ __launch_bounds__(256) void edge_mfma_kernel(
    const unsigned short* __restrict__ wh_g,
    const ushort4* __restrict__ x4b, const float* __restrict__ edge_attr,
    const int* __restrict__ edge_index,
    int* __restrict__ cursor, unsigned short* __restrict__ msgb)
{
    int tid = threadIdx.x, wave = tid >> 6, lane = tid & 63;
    int n = lane & 15, quad = lane >> 4;

    // A-fragments (weights) -> registers, once per wave
    short8 A1[4], A3[4];
    #pragma unroll
    for (int t4 = 0; t4 < 4; t4++) {
        A1[t4] = *(const short8*)(wh_g + W_EW1T + (t4 * 16 + n) * 40 + quad * 8);
        A3[t4] = *(const short8*)(wh_g + W_NW1T + (t4 * 16 + n) * 40 + quad * 8);
    }
    short8 A2[2], A4[2];
    #pragma unroll
    for (int kc = 0; kc < 2; kc++) {
        A2[kc] = *(const short8*)(wh_g + W_EW2T + n * 72 + kc * 32 + quad * 8);
        A4[kc] = *(const short8*)(wh_g + W_NW2T + n * 72 + kc * 32 + quad * 8);
    }

    int s0 = ((quad & 1) * 32 + n) * 4;   // byte index for bpermute (lane*4)
    int s1 = s0 + 64;
    bool hi = (quad & 2) != 0;

    const float4_ Z0 = {0.f, 0.f, 0.f, 0.f};   // one zeroed acc quad, reused

    int t = blockIdx.x * 4 + wave;
    EIn cur0 = load_in(t * 32,      n, quad, edge_index, x4b, edge_attr, cursor);
    EIn cur1 = load_in(t * 32 + 16, n, quad, edge_index, x4b, edge_attr, cursor);

    for (int it = 0; it < EDGE_ITERS; it++) {
        int p0 = __shfl(cur0.pos, n);
        int p1 = __shfl(cur1.pos, n);

        int tn = t + EDGE_WAVES;
        EIn nx0, nx1;
        nx0.w0 = nx0.w1 = nx0.w2 = nx0.w3 = nx0.h0 = nx0.h1 = 0; nx0.pos = 0;
        nx1 = nx0;
        if (it + 1 < EDGE_ITERS) {
            nx0 = load_in(tn * 32,      n, quad, edge_index, x4b, edge_attr, cursor);
            nx1 = load_in(tn * 32 + 16, n, quad, edge_index, x4b, edge_attr, cursor);
        }

        // B1 direct from registers
        BU t0, t1;
        t0.u[0] = cur0.w0; t0.u[1] = cur0.w1; t0.u[2] = cur0.w2; t0.u[3] = cur0.w3;
        t1.u[0] = cur1.w0; t1.u[1] = cur1.w1; t1.u[2] = cur1.w2; t1.u[3] = cur1.w3;
        short8 B1a = t0.s, B1b = t1.s;

        // ---- layer 1: [64ch] x K=32 ----
        unsigned U1a[4][2], U1b[4][2];
        #pragma unroll
        for (int t4 = 0; t4 < 4; t4++) {
            float4_ za = __builtin_amdgcn_mfma_f32_16x16x32_bf16(A1[t4], B1a, Z0, 0, 0, 0);
            float4_ zb = __builtin_amdgcn_mfma_f32_16x16x32_bf16(A1[t4], B1b, Z0, 0, 0, 0);
            U1a[t4][0] = pkbf(fmaxf(za[0], 0.f), fmaxf(za[1], 0.f));
            U1a[t4][1] = pkbf(fmaxf(za[2], 0.f), fmaxf(za[3], 0.f));
            U1b[t4][0] = pkbf(fmaxf(zb[0], 0.f), fmaxf(zb[1], 0.f));
            U1b[t4][1] = pkbf(fmaxf(zb[2], 0.f), fmaxf(zb[3], 0.f));
        }

        short8 B2a0, B2a1, B2b0, B2b1;
        perm64(U1a, s0, s1, hi, B2a0, B2a1);
        perm64(U1b, s0, s1, hi, B2b0, B2b1);
        // bias=1 at k=50: kc=1, quad_b=2, j=2 -> low half of uint[1]
        if (quad == 2) {
            BU fa, fb; fa.s = B2a1; fb.s = B2b1;
            fa.u[1] = (fa.u[1] & 0xFFFF0000u) | 0x3F80u;
            fb.u[1] = (fb.u[1] & 0xFFFF0000u) | 0x3F80u;
            B2a1 = fa.s; B2b1 = fb.s;
        }

        // ---- layer 2: [16ch] x K=64 ----
        float4_ a2a = __builtin_amdgcn_mfma_f32_16x16x32_bf16(A2[0], B2a0, Z0, 0, 0, 0);
        float4_ a2b = __builtin_amdgcn_mfma_f32_16x16x32_bf16(A2[0], B2b0, Z0, 0, 0, 0);
        a2a = __builtin_amdgcn_mfma_f32_16x16x32_bf16(A2[1], B2a1, a2a, 0, 0, 0);
        a2b = __builtin_amdgcn_mfma_f32_16x16x32_bf16(A2[1], B2b1, a2b, 0, 0, 0);

        unsigned U2a[2] = { pkbf(a2a[0], a2a[1]), pkbf(a2a[2], a2a[3]) };
        unsigned U2b[2] = { pkbf(a2b[0], a2b[1]), pkbf(a2b[2], a2b[3]) };

        short8 B3a = perm16(U2a, s0, s1, quad, cur0.h0, cur0.h1);
        short8 B3b = perm16(U2b, s0, s1, quad, cur1.h0, cur1.h1);

        // ---- layer 3: [64ch] x K=32 ----
        unsigned U3a[4][2], U3b[4][2];
        #pragma unroll
        for (int t4 = 0; t4 < 4; t4++) {
            float4_ za = __builtin_amdgcn_mfma_f32_16x16x32_bf16(A3[t4], B3a, Z0, 0, 0, 0);
            float4_ zb = __builtin_amdgcn_mfma_f32_16x16x32_bf16(A3[t4], B3b, Z0, 0, 0, 0);
            U3a[t4][0] = pkbf(fmaxf(za[0], 0.f), fmaxf(za[1], 0.f));
            U3a[t4][1] = pkbf(fmaxf(za[2], 0.f), fmaxf(za[3], 0.f));
            U3b[t4][0] = pkbf(fmaxf(zb[0], 0.f), fmaxf(zb[1], 0.f));
            U3b[t4][1] = pkbf(fmaxf(zb[2], 0.f), fmaxf(zb[3], 0.f));
        }

        short8 B4a0, B4a1, B4b0, B4b1;
        perm64(U3a, s0, s1, hi, B4a0, B4a1);
        perm64(U3b, s0, s1, hi, B4b0, B4b1);
        if (quad == 2) {
            BU fa, fb; fa.s = B4a1; fb.s = B4b1;
            fa.u[1] = (fa.u[1] & 0xFFFF0000u) | 0x3F80u;
            fb.u[1] = (fb.u[1] & 0xFFFF0000u) | 0x3F80u;
            B4a1 = fa.s; B4b1 = fb.s;
        }

        // ---- layer 4: [16ch] x K=64 ----
        float4_ ma = __builtin_amdgcn_mfma_f32_16x16x32_bf16(A4[0], B4a0, Z0, 0, 0, 0);
        float4_ mb = __builtin_amdgcn_mfma_f32_16x16x32_bf16(A4[0], B4b0, Z0, 0, 0, 0);
        ma = __builtin_amdgcn_mfma_f32_16x16x32_bf16(A4[1], B4a1, ma, 0, 0, 0);
        mb = __builtin_amdgcn_mfma_f32_16x16x32_bf16(A4[1], B4b1, mb, 0, 0, 0);

        // bf16 msg: 16 ch * 2B = 32 B/edge; lane writes its 4 channels (8 B)
        uint2 pa, pb;
        pa.x = pkbf(ma[0], ma[1]); pa.y = pkbf(ma[2], ma[3]);
        pb.x = pkbf(mb[0], mb[1]); pb.y = pkbf(mb[2], mb[3]);
        *(uint2*)(msgb + (size_t)p0 * 16 + quad * 4) = pa;
        *(uint2*)(msgb + (size_t)p1 * 16 + quad * 4) = pb;

        cur0 = nx0; cur1 = nx1; t = tn;
    }
}

// ---------- fused gather (CSR segment mean, 4-msg unroll) + pool ----------
__global__ __launch_bounds__(256) void gather_pool_kernel(
    const unsigned short* __restrict__ msgb, const int* __restrict__ scanned,
    const int* __restrict__ counts, const int* __restrict__ batch,
    float* __restrict__ gsum)
{
    __shared__ float acc[64 * 16];
    int n0 = blockIdx.x * 256;
    int n = n0 + threadIdx.x;

    float v[16];
    #pragma unroll
    for (int k = 0; k < 16; k++) v[k] = 0.0f;
    if (n < N_NODES) {
        int start = scanned[n];
        int deg = counts[n];
        const uint4* mp = (const uint4*)(msgb + (size_t)start * 16);
        int j = 0;
        for (; j + 4 <= deg; j += 4) {
            uint4 q0 = mp[2 * j + 0], q1 = mp[2 * j + 1];
            uint4 q2 = mp[2 * j + 2], q3 = mp[2 * j + 3];
            uint4 q4 = mp[2 * j + 4], q5 = mp[2 * j + 5];
            uint4 q6 = mp[2 * j + 6], q7 = mp[2 * j + 7];
            v[0]  += lo16(q0.x) + lo16(q2.x) + lo16(q4.x) + lo16(q6.x);
            v[1]  += hi16(q0.x) + hi16(q2.x) + hi16(q4.x) + hi16(q6.x);
            v[2]  += lo16(q0.y) + lo16(q2.y) + lo16(q4.y) + lo16(q6.y);
            v[3]  += hi16(q0.y) + hi16(q2.y) + hi16(q4.y) + hi16(q6.y);
            v[4]  += lo16(q0.z) + lo16(q2.z) + lo16(q4.z) + lo16(q6.z);
            v[5]  += hi16(q0.z) + hi16(q2.z) + hi16(q4.z) + hi16(q6.z);
            v[6]  += lo16(q0.w) + lo16(q2.w) + lo16(q4.w) + lo16(q6.w);
            v[7]  += hi16(q0.w) + hi16(q2.w) + hi16(q4.w) + hi16(q6.w);
            v[8]  += lo16(q1.x) + lo16(q3.x) + lo16(q5.x) + lo16(q7.x);
            v[9]  += hi16(q1.x) + hi16(q3.x) + hi16(q5.x) + hi16(q7.x);
            v[10] += lo16(q1.y) + lo16(q3.y) + lo16(q5.y) + lo16(q7.y);
            v[11] += hi16(q1.y) + hi16(q3.y) + hi16(q5.y) + hi16(q7.y);
            v[12] += lo16(q1.z) + lo16(q3.z) + lo16(q5.z) + lo16(q7.z);
            v[13] += hi16(q1.z) + hi16(q3.z) + hi16(q5.z) + hi16(q7.z);
            v[14] += lo16(q1.w) + lo16(q3.w) + lo16(q5.w) + lo16(q7.w);
        }
        for (; j < deg; j++) {
            uint4 qa = mp[2 * j + 0], qb = mp[2 * j + 1];
            v[0]  += lo16(qa.x); v[1]  += hi16(qa.x);
            v[2]  += lo16(qa.y); v[3]  += hi16(qa.y);
            v[4]  += lo16(qa.z); v[5]  += hi16(qa.z);
            v[6]  += lo16(qa.w); v[7]  += hi16(qa.w);
            v[8]  += lo16(qb.x); v[9]  += hi16(qb.x);
            v[10] += lo16(qb.y); v[11] += hi16(qb.y);
            v[12] += lo16(qb.z); v[13] += hi16(qb.z);
            v[14] += lo16(qb.w);
        }
        float inv = 1.0f / fmaxf((float)deg, 1.0f);
        #pragma unroll
        for (int k = 0; k < 15; k++) v[k] *= inv;
        v[15] = 1.0f;   // node count
    }

    int gmin = batch[n0];
    int gmax = batch[min(n0 + 255, N_NODES - 1)];
    int range = gmax - gmin + 1;
    if (range <= 64) {
        for (int t = threadIdx.x; t < range * 16; t += 256) acc[t] = 0.0f;
        __syncthreads();
        if (n < N_NODES) {
            int g = batch[n] - gmin;
            float* dst = &acc[g * 16];
            #pragma unroll
            for (int k = 0; k < 16; k++) atomicAdd(&dst[k], v[k]);
        }
        __syncthreads();
        for (int t = threadIdx.x; t < range * 16; t += 256) {
            float w = acc[t];
            if (w != 0.0f) atomicAdd(&gsum[(size_t)gmin * 16 + t], w);
        }
    } else {
        if (n < N_NODES) {
            int g = batch[n];
            float* dst = gsum + (size_t)g * 16;
            #pragma unroll
            for (int k = 0; k < 16; k++) atomicAdd(&dst[k], v[k]);
        }
    }
}

// ---------- head ----------
__global__ __launch_bounds__(512) void head_kernel(
    const float* __restrict__ gsum,
    const float* __restrict__ fc1w, const float* __restrict__ fc1b,
    const float* __restrict__ gamma, const float* __restrict__ beta,
    const float* __restrict__ fc2w, const float* __restrict__ fc2b,
    float* __restrict__ out)
{
    __shared__ float ssum[D5], ssq[D5], smu[D5], sistd[D5];
    int g = threadIdx.x;
    if (g < D5) { ssum[g] = 0.0f; ssq[g] = 0.0f; }
    __syncthreads();

    const float* src = gsum + (size_t)g * 16;
    float inv = 1.0f / fmaxf(src[15], 1.0f);
    float u[D3];
    #pragma unroll
    for (int k = 0; k < D3; k++) u[k] = src[k] * inv;

    float h[D5];
    #pragma unroll
    for (int c = 0; c < D5; c++) h[c] = fc1b[c];
    #pragma unroll
    for (int k = 0; k < D3; k++) {
        float v = u[k];
        #pragma unroll
        for (int c = 0; c < D5; c++) h[c] = fmaf(v, fc1w[k * D5 + c], h[c]);
    }

    int lane = threadIdx.x & 63;
    #pragma unroll
    for (int c = 0; c < D5; c++) {
        float v = h[c];
        float v2 = v * v;
        #pragma unroll
        for (int off = 32; off >= 1; off >>= 1) {
            v  += __shfl_xor(v,  off);
            v2 += __shfl_xor(v2, off);
        }
        if (lane == 0) { atomicAdd(&ssum[c], v); atomicAdd(&ssq[c], v2); }
    }
    __syncthreads();
    if (g < D5) {
        float mu = ssum[g] * (1.0f / NUM_GRAPHS);
        float var = ssq[g] * (1.0f / NUM_GRAPHS) - mu * mu;
        smu[g] = mu;
        sistd[g] = rsqrtf(var + BN_EPS);
    }
    __syncthreads();

    float hn[D5];
    #pragma unroll
    for (int c = 0; c < D5; c++) {
        float v = gamma[c] * (h[c] - smu[c]) * sistd[c] + beta[c];
        hn[c] = fmaxf(v, 0.0f);
    }

    float lg[NCLS];
    #pragma unroll
    for (int j = 0; j < NCLS; j++) lg[j] = fc2b[j];
    #pragma unroll
    for (int c = 0; c < D5; c++) {
        float v = hn[c];
        #pragma unroll
        for (int j = 0; j < NCLS; j++) lg[j] = fmaf(v, fc2w[c * NCLS + j], lg[j]);
    }

    float m = lg[0];
    #pragma unroll
    for (int j = 1; j < NCLS; j++) m = fmaxf(m, lg[j]);
    float se = 0.0f;
    #pragma unroll
    for (int j = 0; j < NCLS; j++) se += expf(lg[j] - m);
    float lse = logf(se);
    #pragma unroll
    for (int j = 0; j < NCLS; j++) out[g * NCLS + j] = lg[j] - m - lse;
}

extern "C" void kernel_launch(void* const* d_in, const int* in_sizes, int n_in,
                              void* d_out, int out_size, void* d_ws, size_t ws_size,
                              hipStream_t stream) {
    const float* x         = (const float*)d_in[0];
    const float* edge_attr = (const float*)d_in[1];
    const float* ew1  = (const float*)d_in[2];
    const float* eb1  = (const float*)d_in[3];
    const float* ew2  = (const float*)d_in[4];
    const float* eb2  = (const float*)d_in[5];
    const float* nw1  = (const float*)d_in[6];
    const float* nb1  = (const float*)d_in[7];
    const float* nw2  = (const float*)d_in[8];
    const float* nb2  = (const float*)d_in[9];
    const float* fc1w = (const float*)d_in[10];
    const float* fc1b = (const float*)d_in[11];
    const float* gamma= (const float*)d_in[12];
    const float* beta = (const float*)d_in[13];
    const float* fc2w = (const float*)d_in[14];
    const float* fc2b = (const float*)d_in[15];
    const int* edge_index = (const int*)d_in[16];
    const int* batch      = (const int*)d_in[17];

    // workspace layout (keep every array 16B-aligned: gctr padded to 16B)
    char* p = (char*)d_ws;
    unsigned short* msgb = (unsigned short*)p; p += (size_t)N_EDGES * 16 * sizeof(unsigned short); // 51.2 MB
    int* counts  = (int*)p;            p += (size_t)N_NODES * sizeof(int);
    int* gctr    = (int*)p;            p += 4 * sizeof(int);                // 16B pad
    int* scanned = (int*)p;            p += (size_t)N_NODES * sizeof(int);
    int* cursor  = (int*)p;            p += (size_t)N_NODES * sizeof(int);
    ushort4* x4b = (ushort4*)p;        p += (size_t)N_NODES * sizeof(ushort4);     // 0.8 MB
    float* gsum  = (float*)p;          p += (size_t)NUM_GRAPHS * 16 * sizeof(float);
    unsigned short* wh = (unsigned short*)p; p += W_TOTAL * sizeof(unsigned short);

    hipMemsetAsync(counts, 0, (size_t)(N_NODES + 4) * sizeof(int), stream);  // counts + gctr pad
    hipMemsetAsync(gsum, 0, (size_t)NUM_GRAPHS * 16 * sizeof(float), stream);

    int egrid = (N_EDGES + 255) / 256;
    int ngrid = (N_NODES + 255) / 256;

    prep_kernel<<<egrid, 256, 0, stream>>>(
        ew1, eb1, ew2, eb2, nw1, nb1, nw2, nb2, wh,
        x, x4b, edge_index, counts);
    scan_kernel<<<NBLK1, 1024, 0, stream>>>(counts, scanned, cursor, gctr);
    edge_mfma_kernel<<<EDGE_BLOCKS, 256, 0, stream>>>(
        wh, x4b, edge_attr, edge_index, cursor, msgb);
    gather_pool_kernel<<<ngrid, 256, 0, stream>>>(
        msgb, scanned, counts, batch, gsum);
    head_kernel<<<1, 512, 0, stream>>>(
        gsum, fc1w, fc1b, gamma, beta, fc2w, fc2b, (float*)d_out);
}